// Round 13
// baseline (205.589 us; speedup 1.0000x reference)
//
#include <hip/hip_runtime.h>
#include <math.h>

typedef __attribute__((ext_vector_type(8))) short short8v;   // 8 bf16 (4 VGPR)
typedef __attribute__((ext_vector_type(4))) float float4v;   // MFMA C/D frag

union uf32 { unsigned int u; float f; };

__device__ __forceinline__ unsigned short f2b(float f) {  // fp32 -> bf16 RNE
  uf32 v; v.f = f;
  unsigned int u = v.u;
  return (unsigned short)((u + 0x7fffu + ((u >> 16) & 1u)) >> 16);
}

// ================= CSR build (XCD-local atomics, atomic-free scatter) =======
__global__ void zero8(int* __restrict__ p, int n) {
  int i = blockIdx.x * 256 + threadIdx.x;
  if (i < n) p[i] = 0;
}

// Per-virtual-XCD histogram; records each edge's local position (removes the
// atomic from the fill pass). vx = blockIdx.x & 7 matches the default
// round-robin block->XCD mapping, so atomics on cnt8[vx] stay XCD-local.
__global__ void hist8(const int* __restrict__ ei, int* __restrict__ cnt8,
                      unsigned short* __restrict__ lpos, int E0, int N) {
  int e = blockIdx.x * 256 + threadIdx.x;
  if (e >= E0 + N) return;
  int vx = blockIdx.x & 7;
  int d = (e < E0) ? ei[E0 + e] : (e - E0);
  lpos[e] = (unsigned short)atomicAdd(&cnt8[vx * N + d], 1);
}

// Fold per-XCD counts -> total degree + per-XCD exclusive base; fused
// block-reduction of degrees into part[].
__global__ void fold8(const int* __restrict__ cnt8, int* __restrict__ base8,
                      int* __restrict__ cnt, int* __restrict__ part, int N) {
  __shared__ int lds[256];
  int d = blockIdx.x * 256 + threadIdx.x;
  int run = 0;
  if (d < N) {
#pragma unroll
    for (int x = 0; x < 8; ++x) {
      int t = cnt8[x * N + d];
      base8[x * N + d] = run;
      run += t;
    }
    cnt[d] = run;
  }
  lds[threadIdx.x] = (d < N) ? run : 0;
  __syncthreads();
  for (int o = 128; o; o >>= 1) {
    if (threadIdx.x < o) lds[threadIdx.x] += lds[threadIdx.x + o];
    __syncthreads();
  }
  if (threadIdx.x == 0) part[blockIdx.x] = lds[0];
}

// single-block exclusive scan with carry (handles any nb)
__global__ void scan_carry(int* __restrict__ part, int nb) {
  __shared__ int lds[256];
  __shared__ int carry;
  if (threadIdx.x == 0) carry = 0;
  __syncthreads();
  for (int t0 = 0; t0 < nb; t0 += 256) {
    int t = t0 + threadIdx.x;
    int v = (t < nb) ? part[t] : 0;
    lds[threadIdx.x] = v;
    __syncthreads();
    for (int o = 1; o < 256; o <<= 1) {
      int x = (threadIdx.x >= o) ? lds[threadIdx.x - o] : 0;
      __syncthreads();
      lds[threadIdx.x] += x;
      __syncthreads();
    }
    if (t < nb) part[t] = carry + lds[threadIdx.x] - v;  // exclusive
    __syncthreads();
    if (threadIdx.x == 255) carry += lds[255];
    __syncthreads();
  }
}

// rp[] scan + fused rb8[x][d] = rp[d] + base8[x][d]
__global__ void scan3(const int* __restrict__ cnt, const int* __restrict__ part,
                      const int* __restrict__ base8, int* __restrict__ rp,
                      int* __restrict__ rb8, int N, int E) {
  __shared__ int lds[256];
  int t = threadIdx.x;
  int idx = blockIdx.x * 256 + t;
  int v = (idx < N) ? cnt[idx] : 0;
  lds[t] = v;
  __syncthreads();
  for (int o = 1; o < 256; o <<= 1) {
    int x = (t >= o) ? lds[t - o] : 0;
    __syncthreads();
    lds[t] += x;
    __syncthreads();
  }
  if (idx < N) {
    const int rpv = part[blockIdx.x] + lds[t] - v;
    rp[idx] = rpv;
#pragma unroll
    for (int x = 0; x < 8; ++x) rb8[x * N + idx] = rpv + base8[x * N + idx];
  }
  if (blockIdx.x == 0 && t == 0) rp[N] = E;
}

// atomic-free scatter: same grid/vx mapping as hist8
__global__ void fillx(const int* __restrict__ ei, const int* __restrict__ rb8,
                      const unsigned short* __restrict__ lpos,
                      int* __restrict__ col, int E0, int N) {
  int e = blockIdx.x * 256 + threadIdx.x;
  if (e >= E0 + N) return;
  int vx = blockIdx.x & 7;
  int s, d;
  if (e < E0) { s = ei[e]; d = ei[E0 + e]; }
  else        { s = e - E0; d = s; }
  col[rb8[vx * N + d] + lpos[e]] = s;
}

// ---------------- all weight packs in one launch ----------------
// fp32 [h][f][c] (strided) -> bf16 MFMA B-frags, element order
// ((kk*4+ct)*4+g)*128 + col*8 + j with f=kk*32+g*8+j, c=ct*16+col.
__global__ void pack_all(const float* __restrict__ emb_w, const float* __restrict__ w0,
                         const float* __restrict__ w1, const float* __restrict__ w2,
                         unsigned short* __restrict__ pE, unsigned short* __restrict__ p0,
                         unsigned short* __restrict__ p1, unsigned short* __restrict__ p2) {
  int b = blockIdx.x;
  const float* w; unsigned short* bp;
  int F, sf, sc, h;
  if (b < 32)       { w = emb_w; bp = pE; F = 128; sf = 1;  sc = 128; h = 0; }
  else if (b < 64)  { b -= 32;  w = w0; bp = p0; F = 64;  sf = 64; sc = 1; h = b / 16; b %= 16; }
  else if (b < 128) { b -= 64;  w = w1; bp = p1; F = 128; sf = 64; sc = 1; h = b / 32; b %= 32; }
  else              { b -= 128; w = w2; bp = p2; F = 128; sf = 64; sc = 1; h = 0; }
  int i = b * 256 + threadIdx.x;
  if (i >= F * 64) return;
  int j = i & 7, colc = (i >> 3) & 15, g = (i >> 7) & 3, ct = (i >> 9) & 3, kk = i >> 11;
  int f = kk * 32 + g * 8 + j;
  int c = ct * 16 + colc;
  float v = w[(size_t)h * F * 64 + (size_t)f * sf + (size_t)c * sc];
  bp[(size_t)h * F * 64 + i] = f2b(v);
}

// ---------------- fused embedding + layer-0 GEMM + scores ----------------
// Block: 256 threads (4 waves), 64-row tile.
// Phase 1: stage x fp32->bf16 in LDS; emb MFMA (packE, NK=4) + bias.
// Phase 2: round-trip emb result through LDS as bf16 (quantization point
//          identical to the old hA buffer); no global intermediate.
// Phase 3: layer-0 MFMA (pack0, NK=2) for both heads + scores -> xhb/si/sj.
__global__ __launch_bounds__(256) void gemm_emb_l0(
    const float* __restrict__ x, const unsigned short* __restrict__ packE,
    const float* __restrict__ emb_b, const unsigned short* __restrict__ pack0,
    const float* __restrict__ a0, unsigned short* __restrict__ xhb,
    float* __restrict__ si, float* __restrict__ sj, int nrows) {
  constexpr int SA = 136;  // ushort stride for 128-wide stage
  constexpr int SB = 72;   // ushort stride for 64-wide emb-out
  __shared__ __align__(16) unsigned short lds[64 * SA];

  const int tid = threadIdx.x;
  const int lane = tid & 63;
  const int wv = tid >> 6;
  const int n0 = blockIdx.x * 64;

  // stage x: 64 rows x 128 fp32 -> bf16
#pragma unroll
  for (int i0 = 0; i0 < 64 * 32; i0 += 256) {
    const int i = i0 + tid;
    const int row = i >> 5, c4 = i & 31;
    int rg = n0 + row;
    if (rg >= nrows) rg = nrows - 1;
    const float4 v = *reinterpret_cast<const float4*>(x + (size_t)rg * 128 + c4 * 4);
    unsigned short* d = lds + row * SA + c4 * 4;
    d[0] = f2b(v.x); d[1] = f2b(v.y); d[2] = f2b(v.z); d[3] = f2b(v.w);
  }
  __syncthreads();

  const int g = lane >> 4;
  const int cl = lane & 15;

  short8v xf[4];
  {
    const unsigned short* ar = lds + (wv * 16 + cl) * SA + g * 8;
#pragma unroll
    for (int kk = 0; kk < 4; ++kk) xf[kk] = *reinterpret_cast<const short8v*>(ar + kk * 32);
  }

  float4v eacc[4];
#pragma unroll
  for (int ct = 0; ct < 4; ++ct) eacc[ct] = (float4v){0.f, 0.f, 0.f, 0.f};
#pragma unroll
  for (int kk = 0; kk < 4; ++kk) {
#pragma unroll
    for (int ct = 0; ct < 4; ++ct) {
      const short8v bf = *reinterpret_cast<const short8v*>(
          packE + ((size_t)((kk * 4 + ct) * 4 + g)) * 128 + cl * 8);
      eacc[ct] = __builtin_amdgcn_mfma_f32_16x16x32_bf16(xf[kk], bf, eacc[ct], 0, 0, 0);
    }
  }
  __syncthreads();  // all waves done reading staged x

  // emb result (+bias) -> LDS bf16 (the layer-0 A tile)
#pragma unroll
  for (int ct = 0; ct < 4; ++ct) {
    const float b = emb_b[ct * 16 + cl];
#pragma unroll
    for (int reg = 0; reg < 4; ++reg) {
      const int row = wv * 16 + g * 4 + reg;
      lds[row * SB + ct * 16 + cl] = f2b(eacc[ct][reg] + b);
    }
  }
  __syncthreads();

  short8v af[2];
  {
    const unsigned short* ar2 = lds + (wv * 16 + cl) * SB + g * 8;
#pragma unroll
    for (int kk = 0; kk < 2; ++kk) af[kk] = *reinterpret_cast<const short8v*>(ar2 + kk * 32);
  }

#pragma unroll
  for (int h = 0; h < 2; ++h) {
    const unsigned short* __restrict__ bph = pack0 + (size_t)h * (64 * 64);

    float4v acc[4];
#pragma unroll
    for (int ct = 0; ct < 4; ++ct) acc[ct] = (float4v){0.f, 0.f, 0.f, 0.f};
#pragma unroll
    for (int kk = 0; kk < 2; ++kk) {
#pragma unroll
      for (int ct = 0; ct < 4; ++ct) {
        const short8v bf = *reinterpret_cast<const short8v*>(
            bph + ((size_t)((kk * 4 + ct) * 4 + g)) * 128 + cl * 8);
        acc[ct] = __builtin_amdgcn_mfma_f32_16x16x32_bf16(af[kk], bf, acc[ct], 0, 0, 0);
      }
    }

    // store bf16 xh
#pragma unroll
    for (int ct = 0; ct < 4; ++ct) {
      const int c = ct * 16 + cl;
#pragma unroll
      for (int reg = 0; reg < 4; ++reg) {
        const int n = n0 + wv * 16 + g * 4 + reg;
        if (n < nrows) xhb[(size_t)n * 128 + h * 64 + c] = f2b(acc[ct][reg]);
      }
    }

    // scores
    float pi[4] = {0.f, 0.f, 0.f, 0.f}, pj[4] = {0.f, 0.f, 0.f, 0.f};
#pragma unroll
    for (int ct = 0; ct < 4; ++ct) {
      const float av = a0[h * 128 + ct * 16 + cl];
      const float bv = a0[h * 128 + 64 + ct * 16 + cl];
#pragma unroll
      for (int reg = 0; reg < 4; ++reg) {
        pi[reg] = fmaf(acc[ct][reg], av, pi[reg]);
        pj[reg] = fmaf(acc[ct][reg], bv, pj[reg]);
      }
    }
#pragma unroll
    for (int reg = 0; reg < 4; ++reg) {
#pragma unroll
      for (int o = 8; o; o >>= 1) {
        pi[reg] += __shfl_xor(pi[reg], o, 64);
        pj[reg] += __shfl_xor(pj[reg], o, 64);
      }
    }
    if (cl == 0) {
#pragma unroll
      for (int reg = 0; reg < 4; ++reg) {
        const int n = n0 + wv * 16 + g * 4 + reg;
        if (n < nrows) {
          si[(size_t)n * 2 + h] = pi[reg];
          sj[(size_t)n * 2 + h] = pj[reg];
        }
      }
    }
  }
}

// ---------------- MFMA GEMM + attention scores (all heads per block) --------
// Block: 256 threads (4 waves), 64-row tile; loops h=0..H-1 with A-frags held
// in registers. B-frags from packed global (L2-hot). bf16 in, fp32 acc.
template <int F, int H, bool SCORES, bool OBF>
__global__ __launch_bounds__(256) void gemm_mfma(
    const unsigned short* __restrict__ in, const unsigned short* __restrict__ bp,
    const float* __restrict__ a, void* __restrict__ xh_out,
    float* __restrict__ si, float* __restrict__ sj, int nrows) {
  constexpr int SA = F + 8;
  constexpr int NK = F / 32;
  constexpr int HC = H * 64;
  __shared__ __align__(16) unsigned short A_lds[64 * SA];

  const int tid = threadIdx.x;
  const int lane = tid & 63;
  const int wv = tid >> 6;
  const int n0 = blockIdx.x * 64;

  {
    constexpr int NCH = 64 * F / 8;
#pragma unroll
    for (int i0 = 0; i0 < NCH; i0 += 256) {
      const int i = i0 + tid;
      const int row = i / (F / 8);
      const int c8 = i % (F / 8);
      int rg = n0 + row;
      if (rg >= nrows) rg = nrows - 1;
      const short8v v = *reinterpret_cast<const short8v*>(in + (size_t)rg * F + c8 * 8);
      *reinterpret_cast<short8v*>(A_lds + row * SA + c8 * 8) = v;
    }
  }
  __syncthreads();

  const int g = lane >> 4;
  const int cl = lane & 15;

  short8v af[NK];
  const unsigned short* ar = A_lds + (wv * 16 + cl) * SA + g * 8;
#pragma unroll
  for (int kk = 0; kk < NK; ++kk) af[kk] = *reinterpret_cast<const short8v*>(ar + kk * 32);

#pragma unroll
  for (int h = 0; h < H; ++h) {
    const unsigned short* __restrict__ bph = bp + (size_t)h * (F * 64);

    float4v acc[4];
#pragma unroll
    for (int ct = 0; ct < 4; ++ct) acc[ct] = (float4v){0.f, 0.f, 0.f, 0.f};

#pragma unroll
    for (int kk = 0; kk < NK; ++kk) {
#pragma unroll
      for (int ct = 0; ct < 4; ++ct) {
        const short8v bf = *reinterpret_cast<const short8v*>(
            bph + ((size_t)((kk * 4 + ct) * 4 + g)) * 128 + cl * 8);
        acc[ct] = __builtin_amdgcn_mfma_f32_16x16x32_bf16(af[kk], bf, acc[ct], 0, 0, 0);
      }
    }

#pragma unroll
    for (int ct = 0; ct < 4; ++ct) {
      const int c = ct * 16 + cl;
#pragma unroll
      for (int reg = 0; reg < 4; ++reg) {
        const int n = n0 + wv * 16 + g * 4 + reg;
        if (n < nrows) {
          const size_t idx = (size_t)n * HC + h * 64 + c;
          if (OBF) ((unsigned short*)xh_out)[idx] = f2b(acc[ct][reg]);
          else     ((float*)xh_out)[idx] = acc[ct][reg];
        }
      }
    }

    if (SCORES) {
      float pi[4] = {0.f, 0.f, 0.f, 0.f}, pj[4] = {0.f, 0.f, 0.f, 0.f};
#pragma unroll
      for (int ct = 0; ct < 4; ++ct) {
        const float av = a[h * 128 + ct * 16 + cl];
        const float bv = a[h * 128 + 64 + ct * 16 + cl];
#pragma unroll
        for (int reg = 0; reg < 4; ++reg) {
          pi[reg] = fmaf(acc[ct][reg], av, pi[reg]);
          pj[reg] = fmaf(acc[ct][reg], bv, pj[reg]);
        }
      }
#pragma unroll
      for (int reg = 0; reg < 4; ++reg) {
#pragma unroll
        for (int o = 8; o; o >>= 1) {
          pi[reg] += __shfl_xor(pi[reg], o, 64);
          pj[reg] += __shfl_xor(pj[reg], o, 64);
        }
      }
      if (cl == 0) {
#pragma unroll
        for (int reg = 0; reg < 4; ++reg) {
          const int n = n0 + wv * 16 + g * 4 + reg;
          if (n < nrows) {
            si[(size_t)n * H + h] = pi[reg];
            sj[(size_t)n * H + h] = pj[reg];
          }
        }
      }
    }
  }
}

// ---------------- per-node softmax aggregation (no-max, 4-feature lanes) ----
// One wave per node, 32-edge chunks.
// Softmax WITHOUT running-max: p = exp(min(al, 75)). Mathematically identical
// ratio (reference subtracts segment_max only for overflow safety; Xavier-init
// scores are |al| << 75 so the clamp never binds). Removes the 5-shfl max
// reduce from the critical path + all rescale logic; den is accumulated
// per-lane and reduced ONCE per node at the end.
// Accumulate: lane owns 4 features (uint2 = 8 B gather).
//   H==2: wave halves process alternate edges (2 in flight); lane's features
//     4*(lane&31).. of the 128-wide row; its head = (lane&16)>>4; final
//     shfl_xor(32) combine.
//   H==1: quarter-groups process 4 edges in flight; features 4*(lane&15)..;
//     final shfl_xor(32)+(16) combine.
// Invalid edges have p=0 (and s=0 -> harmless row-0 load), so partial chunks
// need no branches; shfl sources stay <= 31.
template <int H, bool OBF>
__global__ __launch_bounds__(256) void agg_kernel(
    const unsigned short* __restrict__ xh, const float* __restrict__ si_g,
    const float* __restrict__ sj_g, const int* __restrict__ rp,
    const int* __restrict__ col, void* __restrict__ out, int N) {
  constexpr int HC = H * 64;
  const int lane = threadIdx.x & 63;
  const int n = blockIdx.x * 4 + (threadIdx.x >> 6);
  if (n >= N) return;
  const int el = lane & 31;
  const int hl = (H == 2) ? (lane >> 5) : 0;

  const int base = rp[n];
  const int deg = rp[n + 1] - base;
  const float siv = si_g[(size_t)n * H + hl];

  const int egrp = (H == 2) ? (lane >> 5) : (lane >> 4);   // edge-group id
  constexpr int STEP = (H == 2) ? 2 : 4;                    // edges per loop step
  const int qsrc = (H == 2) ? (egrp + ((lane & 16) << 1)) : egrp;  // p source lane offset
  const unsigned short* xrow = xh + ((H == 2) ? (unsigned)(lane & 31) * 4
                                              : (unsigned)(lane & 15) * 4);

  float den_l = 0.f;
  float a0 = 0.f, a1 = 0.f, a2 = 0.f, a3 = 0.f;

  for (int start = 0; start < deg; start += 32) {
    const int k = start + el;
    const bool vld = k < deg;
    const int s = vld ? col[base + k] : 0;
    float p = 0.f;
    if (vld) {
      const float t = siv + sj_g[(size_t)s * H + hl];
      const float al = (t > 0.f) ? t : 0.2f * t;
      p = __expf(fminf(al, 75.f));
    }
    den_l += p;

    const int cc = min(32, deg - start);
    int kk = 0;
    for (; kk + 4 * STEP <= cc; kk += 4 * STEP) {
      int sb[4]; float qb[4]; uint2 uv[4];
#pragma unroll
      for (int u = 0; u < 4; ++u) {
        const int e = kk + u * STEP;
        sb[u] = __shfl(s, e + egrp, 64);
        qb[u] = __shfl(p, e + qsrc, 64);
      }
#pragma unroll
      for (int u = 0; u < 4; ++u)
        uv[u] = *reinterpret_cast<const uint2*>(xrow + (size_t)sb[u] * HC);
#pragma unroll
      for (int u = 0; u < 4; ++u) {
        uf32 f0, f1, f2, f3;
        f0.u = uv[u].x << 16; f1.u = uv[u].x & 0xffff0000u;
        f2.u = uv[u].y << 16; f3.u = uv[u].y & 0xffff0000u;
        a0 = fmaf(qb[u], f0.f, a0);
        a1 = fmaf(qb[u], f1.f, a1);
        a2 = fmaf(qb[u], f2.f, a2);
        a3 = fmaf(qb[u], f3.f, a3);
      }
    }
    for (; kk < cc; kk += STEP) {
      const int sb = __shfl(s, kk + egrp, 64);
      const float qb = __shfl(p, kk + qsrc, 64);
      const uint2 uv = *reinterpret_cast<const uint2*>(xrow + (size_t)sb * HC);
      uf32 f0, f1, f2, f3;
      f0.u = uv.x << 16; f1.u = uv.x & 0xffff0000u;
      f2.u = uv.y << 16; f3.u = uv.y & 0xffff0000u;
      a0 = fmaf(qb, f0.f, a0);
      a1 = fmaf(qb, f1.f, a1);
      a2 = fmaf(qb, f2.f, a2);
      a3 = fmaf(qb, f3.f, a3);
    }
  }

  // cross-group feature combine
  a0 += __shfl_xor(a0, 32, 64);
  a1 += __shfl_xor(a1, 32, 64);
  a2 += __shfl_xor(a2, 32, 64);
  a3 += __shfl_xor(a3, 32, 64);
  if (H == 1) {
    a0 += __shfl_xor(a0, 16, 64);
    a1 += __shfl_xor(a1, 16, 64);
    a2 += __shfl_xor(a2, 16, 64);
    a3 += __shfl_xor(a3, 16, 64);
  }

  // den reduce: per-32-group sum (= per-head for H==2; duplicated halves for H==1)
#pragma unroll
  for (int o = 16; o; o >>= 1) den_l += __shfl_xor(den_l, o, 64);
  const float den = (H == 2) ? __shfl(den_l, (lane & 16) << 1, 64) : den_l;

  const int nwrite = (H == 2) ? 32 : 16;
  if (lane < nwrite) {
    const float invd = 1.f / (den + 1e-16f);
    float v0 = a0 * invd, v1 = a1 * invd, v2 = a2 * invd, v3 = a3 * invd;
    v0 = (v0 > 0.f) ? v0 : expm1f(v0);
    v1 = (v1 > 0.f) ? v1 : expm1f(v1);
    v2 = (v2 > 0.f) ? v2 : expm1f(v2);
    v3 = (v3 > 0.f) ? v3 : expm1f(v3);
    if (OBF) {
      uint2 pk;
      pk.x = (unsigned int)f2b(v0) | ((unsigned int)f2b(v1) << 16);
      pk.y = (unsigned int)f2b(v2) | ((unsigned int)f2b(v3) << 16);
      *reinterpret_cast<uint2*>((unsigned short*)out + (size_t)n * HC + lane * 4) = pk;
    } else {
      float4 o4; o4.x = v0; o4.y = v1; o4.z = v2; o4.w = v3;
      *reinterpret_cast<float4*>((float*)out + (size_t)n * HC + lane * 4) = o4;
    }
  }
}

// ---------------- launch ----------------
extern "C" void kernel_launch(void* const* d_in, const int* in_sizes, int n_in,
                              void* d_out, int out_size, void* d_ws, size_t ws_size,
                              hipStream_t stream) {
  const float* x     = (const float*)d_in[0];
  const int*   ei    = (const int*)d_in[1];
  const float* emb_w = (const float*)d_in[2];
  const float* emb_b = (const float*)d_in[3];
  const float* w0    = (const float*)d_in[4];
  const float* a0    = (const float*)d_in[5];
  const float* w1    = (const float*)d_in[6];
  const float* a1    = (const float*)d_in[7];
  const float* w2    = (const float*)d_in[8];
  const float* a2    = (const float*)d_in[9];

  const int IN_CH = 128;
  int N  = in_sizes[0] / IN_CH;   // 50000
  int E0 = in_sizes[1] / 2;       // 800000
  int E  = E0 + N;                // with self-loops

  // workspace carve (256B aligned)
  char* p = (char*)d_ws;
  auto alloc = [&](size_t bytes) -> char* {
    char* r = p;
    p += (bytes + 255) & ~(size_t)255;
    return r;
  };
  unsigned short* hA  = (unsigned short*)alloc((size_t)N * 128 * 2);
  unsigned short* hB  = (unsigned short*)alloc((size_t)N * 128 * 2);
  unsigned short* xhb = (unsigned short*)alloc((size_t)N * 128 * 2);
  float* si   = (float*)alloc((size_t)N * 2 * 4);
  float* sj   = (float*)alloc((size_t)N * 2 * 4);
  unsigned short* packE = (unsigned short*)alloc(128 * 64 * 2);
  unsigned short* pack0 = (unsigned short*)alloc(2 * 64 * 64 * 2);
  unsigned short* pack1 = (unsigned short*)alloc(2 * 128 * 64 * 2);
  unsigned short* pack2 = (unsigned short*)alloc(128 * 64 * 2);
  int* rp    = (int*)alloc((size_t)(N + 1) * 4);
  int* cnt   = (int*)alloc((size_t)N * 4);
  int* cnt8  = (int*)alloc((size_t)8 * N * 4);
  int* base8 = (int*)alloc((size_t)8 * N * 4);
  int* rb8   = (int*)alloc((size_t)8 * N * 4);
  unsigned short* lpos = (unsigned short*)alloc((size_t)E * 2);
  int* col   = (int*)alloc((size_t)E * 4);
  int* part  = (int*)alloc(1024);

  dim3 blk(256);
  int gN = (N + 255) / 256;     // 196
  int gE = (E + 255) / 256;

  // CSR build (atomic-light)
  zero8<<<(8 * N + 255) / 256, blk, 0, stream>>>(cnt8, 8 * N);
  hist8<<<gE, blk, 0, stream>>>(ei, cnt8, lpos, E0, N);
  fold8<<<gN, blk, 0, stream>>>(cnt8, base8, cnt, part, N);
  scan_carry<<<1, blk, 0, stream>>>(part, gN);
  scan3<<<gN, blk, 0, stream>>>(cnt, part, base8, rp, rb8, N, E);
  fillx<<<gE, blk, 0, stream>>>(ei, rb8, lpos, col, E0, N);

  // all weight packs in one launch
  pack_all<<<160, blk, 0, stream>>>(emb_w, w0, w1, w2, packE, pack0, pack1, pack2);

  int gR = (N + 63) / 64;  // 782

  // fused embedding + layer 0 (both heads), bf16 out + scores
  gemm_emb_l0<<<gR, blk, 0, stream>>>(x, packE, emb_b, pack0, a0, xhb, si, sj, N);
  agg_kernel<2, true><<<(N + 3) / 4, blk, 0, stream>>>(xhb, si, sj, rp, col, hB, N);

  // layer 1: F=128, H=2
  gemm_mfma<128, 2, true, true><<<gR, blk, 0, stream>>>(hB, pack1, a1, xhb, si, sj, N);
  agg_kernel<2, true><<<(N + 3) / 4, blk, 0, stream>>>(xhb, si, sj, rp, col, hA, N);

  // layer 2: F=128, H=1 -> output fp32
  gemm_mfma<128, 1, true, true><<<gR, blk, 0, stream>>>(hA, pack2, a2, xhb, si, sj, N);
  agg_kernel<1, false><<<(N + 3) / 4, blk, 0, stream>>>(xhb, si, sj, rp, col, (float*)d_out, N);
}

// Round 14
// 200.166 us; speedup vs baseline: 1.0271x; 1.0271x over previous
//
#include <hip/hip_runtime.h>
#include <math.h>

typedef __attribute__((ext_vector_type(8))) short short8v;   // 8 bf16 (4 VGPR)
typedef __attribute__((ext_vector_type(4))) float float4v;   // MFMA C/D frag

union uf32 { unsigned int u; float f; };

__device__ __forceinline__ unsigned short f2b(float f) {  // fp32 -> bf16 RNE
  uf32 v; v.f = f;
  unsigned int u = v.u;
  return (unsigned short)((u + 0x7fffu + ((u >> 16) & 1u)) >> 16);
}

// ================= CSR build (XCD-local atomics, atomic-free scatter) =======

// Per-virtual-XCD histogram; records each edge's local position (removes the
// atomic from the fill pass). vx = blockIdx.x & 7 matches the default
// round-robin block->XCD mapping, so atomics on cnt8[vx] stay XCD-local.
__global__ void hist8(const int* __restrict__ ei, int* __restrict__ cnt8,
                      unsigned short* __restrict__ lpos, int E0, int N) {
  int e = blockIdx.x * 256 + threadIdx.x;
  if (e >= E0 + N) return;
  int vx = blockIdx.x & 7;
  int d = (e < E0) ? ei[E0 + e] : (e - E0);
  lpos[e] = (unsigned short)atomicAdd(&cnt8[vx * N + d], 1);
}

// Fold per-XCD counts -> total degree + per-XCD exclusive base; fused
// block-reduction of degrees into part[].
__global__ void fold8(const int* __restrict__ cnt8, int* __restrict__ base8,
                      int* __restrict__ cnt, int* __restrict__ part, int N) {
  __shared__ int lds[256];
  int d = blockIdx.x * 256 + threadIdx.x;
  int run = 0;
  if (d < N) {
#pragma unroll
    for (int x = 0; x < 8; ++x) {
      int t = cnt8[x * N + d];
      base8[x * N + d] = run;
      run += t;
    }
    cnt[d] = run;
  }
  lds[threadIdx.x] = (d < N) ? run : 0;
  __syncthreads();
  for (int o = 128; o; o >>= 1) {
    if (threadIdx.x < o) lds[threadIdx.x] += lds[threadIdx.x + o];
    __syncthreads();
  }
  if (threadIdx.x == 0) part[blockIdx.x] = lds[0];
}

// single-block exclusive scan with carry (handles any nb)
__global__ void scan_carry(int* __restrict__ part, int nb) {
  __shared__ int lds[256];
  __shared__ int carry;
  if (threadIdx.x == 0) carry = 0;
  __syncthreads();
  for (int t0 = 0; t0 < nb; t0 += 256) {
    int t = t0 + threadIdx.x;
    int v = (t < nb) ? part[t] : 0;
    lds[threadIdx.x] = v;
    __syncthreads();
    for (int o = 1; o < 256; o <<= 1) {
      int x = (threadIdx.x >= o) ? lds[threadIdx.x - o] : 0;
      __syncthreads();
      lds[threadIdx.x] += x;
      __syncthreads();
    }
    if (t < nb) part[t] = carry + lds[threadIdx.x] - v;  // exclusive
    __syncthreads();
    if (threadIdx.x == 255) carry += lds[255];
    __syncthreads();
  }
}

// rp[] scan + fused rb8[x][d] = rp[d] + base8[x][d]
__global__ void scan3(const int* __restrict__ cnt, const int* __restrict__ part,
                      const int* __restrict__ base8, int* __restrict__ rp,
                      int* __restrict__ rb8, int N, int E) {
  __shared__ int lds[256];
  int t = threadIdx.x;
  int idx = blockIdx.x * 256 + t;
  int v = (idx < N) ? cnt[idx] : 0;
  lds[t] = v;
  __syncthreads();
  for (int o = 1; o < 256; o <<= 1) {
    int x = (t >= o) ? lds[t - o] : 0;
    __syncthreads();
    lds[t] += x;
    __syncthreads();
  }
  if (idx < N) {
    const int rpv = part[blockIdx.x] + lds[t] - v;
    rp[idx] = rpv;
#pragma unroll
    for (int x = 0; x < 8; ++x) rb8[x * N + idx] = rpv + base8[x * N + idx];
  }
  if (blockIdx.x == 0 && t == 0) rp[N] = E;
}

// atomic-free scatter: same grid/vx mapping as hist8
__global__ void fillx(const int* __restrict__ ei, const int* __restrict__ rb8,
                      const unsigned short* __restrict__ lpos,
                      int* __restrict__ col, int E0, int N) {
  int e = blockIdx.x * 256 + threadIdx.x;
  if (e >= E0 + N) return;
  int vx = blockIdx.x & 7;
  int s, d;
  if (e < E0) { s = ei[e]; d = ei[E0 + e]; }
  else        { s = e - E0; d = s; }
  col[rb8[vx * N + d] + lpos[e]] = s;
}

// ---------------- setup: zero cnt8 + all weight packs in ONE launch ---------
// blocks [0, gZ): zero cnt8 (8*N ints). blocks [gZ, gZ+160): weight packs.
// Pack element order ((kk*4+ct)*4+g)*128 + col*8 + j with f=kk*32+g*8+j,
// c=ct*16+col; fp32 [h][f][c] (strided) -> bf16 MFMA B-frags.
__global__ void setup_kernel(int* __restrict__ cnt8, int nz, int gZ,
                             const float* __restrict__ emb_w, const float* __restrict__ w0,
                             const float* __restrict__ w1, const float* __restrict__ w2,
                             unsigned short* __restrict__ pE, unsigned short* __restrict__ p0,
                             unsigned short* __restrict__ p1, unsigned short* __restrict__ p2) {
  if ((int)blockIdx.x < gZ) {
    int i = blockIdx.x * 256 + threadIdx.x;
    if (i < nz) cnt8[i] = 0;
    return;
  }
  int b = blockIdx.x - gZ;
  const float* w; unsigned short* bp;
  int F, sf, sc, h;
  if (b < 32)       { w = emb_w; bp = pE; F = 128; sf = 1;  sc = 128; h = 0; }
  else if (b < 64)  { b -= 32;  w = w0; bp = p0; F = 64;  sf = 64; sc = 1; h = b / 16; b %= 16; }
  else if (b < 128) { b -= 64;  w = w1; bp = p1; F = 128; sf = 64; sc = 1; h = b / 32; b %= 32; }
  else              { b -= 128; w = w2; bp = p2; F = 128; sf = 64; sc = 1; h = 0; }
  int i = b * 256 + threadIdx.x;
  if (i >= F * 64) return;
  int j = i & 7, colc = (i >> 3) & 15, g = (i >> 7) & 3, ct = (i >> 9) & 3, kk = i >> 11;
  int f = kk * 32 + g * 8 + j;
  int c = ct * 16 + colc;
  float v = w[(size_t)h * F * 64 + (size_t)f * sf + (size_t)c * sc];
  bp[(size_t)h * F * 64 + i] = f2b(v);
}

// ---------------- fused embedding + layer-0 GEMM + scores ----------------
// Block: 256 threads (4 waves), 64-row tile.
// Phase 1: stage x fp32->bf16 in LDS; emb MFMA (packE, NK=4) + bias.
// Phase 2: round-trip emb result through LDS as bf16 (quantization point
//          identical to the old hA buffer); no global intermediate.
// Phase 3: layer-0 MFMA (pack0, NK=2) for both heads + scores -> xhb/si/sj.
__global__ __launch_bounds__(256) void gemm_emb_l0(
    const float* __restrict__ x, const unsigned short* __restrict__ packE,
    const float* __restrict__ emb_b, const unsigned short* __restrict__ pack0,
    const float* __restrict__ a0, unsigned short* __restrict__ xhb,
    float* __restrict__ si, float* __restrict__ sj, int nrows) {
  constexpr int SA = 136;  // ushort stride for 128-wide stage
  constexpr int SB = 72;   // ushort stride for 64-wide emb-out
  __shared__ __align__(16) unsigned short lds[64 * SA];

  const int tid = threadIdx.x;
  const int lane = tid & 63;
  const int wv = tid >> 6;
  const int n0 = blockIdx.x * 64;

  // stage x: 64 rows x 128 fp32 -> bf16
#pragma unroll
  for (int i0 = 0; i0 < 64 * 32; i0 += 256) {
    const int i = i0 + tid;
    const int row = i >> 5, c4 = i & 31;
    int rg = n0 + row;
    if (rg >= nrows) rg = nrows - 1;
    const float4 v = *reinterpret_cast<const float4*>(x + (size_t)rg * 128 + c4 * 4);
    unsigned short* d = lds + row * SA + c4 * 4;
    d[0] = f2b(v.x); d[1] = f2b(v.y); d[2] = f2b(v.z); d[3] = f2b(v.w);
  }
  __syncthreads();

  const int g = lane >> 4;
  const int cl = lane & 15;

  short8v xf[4];
  {
    const unsigned short* ar = lds + (wv * 16 + cl) * SA + g * 8;
#pragma unroll
    for (int kk = 0; kk < 4; ++kk) xf[kk] = *reinterpret_cast<const short8v*>(ar + kk * 32);
  }

  float4v eacc[4];
#pragma unroll
  for (int ct = 0; ct < 4; ++ct) eacc[ct] = (float4v){0.f, 0.f, 0.f, 0.f};
#pragma unroll
  for (int kk = 0; kk < 4; ++kk) {
#pragma unroll
    for (int ct = 0; ct < 4; ++ct) {
      const short8v bf = *reinterpret_cast<const short8v*>(
          packE + ((size_t)((kk * 4 + ct) * 4 + g)) * 128 + cl * 8);
      eacc[ct] = __builtin_amdgcn_mfma_f32_16x16x32_bf16(xf[kk], bf, eacc[ct], 0, 0, 0);
    }
  }
  __syncthreads();  // all waves done reading staged x

  // emb result (+bias) -> LDS bf16 (the layer-0 A tile)
#pragma unroll
  for (int ct = 0; ct < 4; ++ct) {
    const float b = emb_b[ct * 16 + cl];
#pragma unroll
    for (int reg = 0; reg < 4; ++reg) {
      const int row = wv * 16 + g * 4 + reg;
      lds[row * SB + ct * 16 + cl] = f2b(eacc[ct][reg] + b);
    }
  }
  __syncthreads();

  short8v af[2];
  {
    const unsigned short* ar2 = lds + (wv * 16 + cl) * SB + g * 8;
#pragma unroll
    for (int kk = 0; kk < 2; ++kk) af[kk] = *reinterpret_cast<const short8v*>(ar2 + kk * 32);
  }

#pragma unroll
  for (int h = 0; h < 2; ++h) {
    const unsigned short* __restrict__ bph = pack0 + (size_t)h * (64 * 64);

    float4v acc[4];
#pragma unroll
    for (int ct = 0; ct < 4; ++ct) acc[ct] = (float4v){0.f, 0.f, 0.f, 0.f};
#pragma unroll
    for (int kk = 0; kk < 2; ++kk) {
#pragma unroll
      for (int ct = 0; ct < 4; ++ct) {
        const short8v bf = *reinterpret_cast<const short8v*>(
            bph + ((size_t)((kk * 4 + ct) * 4 + g)) * 128 + cl * 8);
        acc[ct] = __builtin_amdgcn_mfma_f32_16x16x32_bf16(af[kk], bf, acc[ct], 0, 0, 0);
      }
    }

    // store bf16 xh
#pragma unroll
    for (int ct = 0; ct < 4; ++ct) {
      const int c = ct * 16 + cl;
#pragma unroll
      for (int reg = 0; reg < 4; ++reg) {
        const int n = n0 + wv * 16 + g * 4 + reg;
        if (n < nrows) xhb[(size_t)n * 128 + h * 64 + c] = f2b(acc[ct][reg]);
      }
    }

    // scores
    float pi[4] = {0.f, 0.f, 0.f, 0.f}, pj[4] = {0.f, 0.f, 0.f, 0.f};
#pragma unroll
    for (int ct = 0; ct < 4; ++ct) {
      const float av = a0[h * 128 + ct * 16 + cl];
      const float bv = a0[h * 128 + 64 + ct * 16 + cl];
#pragma unroll
      for (int reg = 0; reg < 4; ++reg) {
        pi[reg] = fmaf(acc[ct][reg], av, pi[reg]);
        pj[reg] = fmaf(acc[ct][reg], bv, pj[reg]);
      }
    }
#pragma unroll
    for (int reg = 0; reg < 4; ++reg) {
#pragma unroll
      for (int o = 8; o; o >>= 1) {
        pi[reg] += __shfl_xor(pi[reg], o, 64);
        pj[reg] += __shfl_xor(pj[reg], o, 64);
      }
    }
    if (cl == 0) {
#pragma unroll
      for (int reg = 0; reg < 4; ++reg) {
        const int n = n0 + wv * 16 + g * 4 + reg;
        if (n < nrows) {
          si[(size_t)n * 2 + h] = pi[reg];
          sj[(size_t)n * 2 + h] = pj[reg];
        }
      }
    }
  }
}

// ---------------- MFMA GEMM + attention scores (all heads per block) --------
// Block: 256 threads (4 waves), 64-row tile; loops h=0..H-1 with A-frags held
// in registers. B-frags from packed global (L2-hot). bf16 in, fp32 acc.
template <int F, int H, bool SCORES, bool OBF>
__global__ __launch_bounds__(256) void gemm_mfma(
    const unsigned short* __restrict__ in, const unsigned short* __restrict__ bp,
    const float* __restrict__ a, void* __restrict__ xh_out,
    float* __restrict__ si, float* __restrict__ sj, int nrows) {
  constexpr int SA = F + 8;
  constexpr int NK = F / 32;
  constexpr int HC = H * 64;
  __shared__ __align__(16) unsigned short A_lds[64 * SA];

  const int tid = threadIdx.x;
  const int lane = tid & 63;
  const int wv = tid >> 6;
  const int n0 = blockIdx.x * 64;

  {
    constexpr int NCH = 64 * F / 8;
#pragma unroll
    for (int i0 = 0; i0 < NCH; i0 += 256) {
      const int i = i0 + tid;
      const int row = i / (F / 8);
      const int c8 = i % (F / 8);
      int rg = n0 + row;
      if (rg >= nrows) rg = nrows - 1;
      const short8v v = *reinterpret_cast<const short8v*>(in + (size_t)rg * F + c8 * 8);
      *reinterpret_cast<short8v*>(A_lds + row * SA + c8 * 8) = v;
    }
  }
  __syncthreads();

  const int g = lane >> 4;
  const int cl = lane & 15;

  short8v af[NK];
  const unsigned short* ar = A_lds + (wv * 16 + cl) * SA + g * 8;
#pragma unroll
  for (int kk = 0; kk < NK; ++kk) af[kk] = *reinterpret_cast<const short8v*>(ar + kk * 32);

#pragma unroll
  for (int h = 0; h < H; ++h) {
    const unsigned short* __restrict__ bph = bp + (size_t)h * (F * 64);

    float4v acc[4];
#pragma unroll
    for (int ct = 0; ct < 4; ++ct) acc[ct] = (float4v){0.f, 0.f, 0.f, 0.f};

#pragma unroll
    for (int kk = 0; kk < NK; ++kk) {
#pragma unroll
      for (int ct = 0; ct < 4; ++ct) {
        const short8v bf = *reinterpret_cast<const short8v*>(
            bph + ((size_t)((kk * 4 + ct) * 4 + g)) * 128 + cl * 8);
        acc[ct] = __builtin_amdgcn_mfma_f32_16x16x32_bf16(af[kk], bf, acc[ct], 0, 0, 0);
      }
    }

#pragma unroll
    for (int ct = 0; ct < 4; ++ct) {
      const int c = ct * 16 + cl;
#pragma unroll
      for (int reg = 0; reg < 4; ++reg) {
        const int n = n0 + wv * 16 + g * 4 + reg;
        if (n < nrows) {
          const size_t idx = (size_t)n * HC + h * 64 + c;
          if (OBF) ((unsigned short*)xh_out)[idx] = f2b(acc[ct][reg]);
          else     ((float*)xh_out)[idx] = acc[ct][reg];
        }
      }
    }

    if (SCORES) {
      float pi[4] = {0.f, 0.f, 0.f, 0.f}, pj[4] = {0.f, 0.f, 0.f, 0.f};
#pragma unroll
      for (int ct = 0; ct < 4; ++ct) {
        const float av = a[h * 128 + ct * 16 + cl];
        const float bv = a[h * 128 + 64 + ct * 16 + cl];
#pragma unroll
        for (int reg = 0; reg < 4; ++reg) {
          pi[reg] = fmaf(acc[ct][reg], av, pi[reg]);
          pj[reg] = fmaf(acc[ct][reg], bv, pj[reg]);
        }
      }
#pragma unroll
      for (int reg = 0; reg < 4; ++reg) {
#pragma unroll
        for (int o = 8; o; o >>= 1) {
          pi[reg] += __shfl_xor(pi[reg], o, 64);
          pj[reg] += __shfl_xor(pj[reg], o, 64);
        }
      }
      if (cl == 0) {
#pragma unroll
        for (int reg = 0; reg < 4; ++reg) {
          const int n = n0 + wv * 16 + g * 4 + reg;
          if (n < nrows) {
            si[(size_t)n * H + h] = pi[reg];
            sj[(size_t)n * H + h] = pj[reg];
          }
        }
      }
    }
  }
}

// ---------------- per-node online-softmax aggregation (shfl broadcast) ------
// One wave per node, 32-edge chunks (round-12 verified best: pipelinable
// ds_bpermute broadcasts, uint gather, 8-deep unroll, first-chunk max skip).
// H==2: lane half = head; lane loads uint (2 bf16) -> one coalesced 256 B row
// per edge. H==1: halves process alternate edges; final shfl_xor(32) combine.
template <int H, bool OBF>
__global__ __launch_bounds__(256) void agg_kernel(
    const unsigned short* __restrict__ xh, const float* __restrict__ si_g,
    const float* __restrict__ sj_g, const int* __restrict__ rp,
    const int* __restrict__ col, void* __restrict__ out, int N) {
  constexpr int HC = H * 64;
  const int lane = threadIdx.x & 63;
  const int n = blockIdx.x * 4 + (threadIdx.x >> 6);
  if (n >= N) return;
  const int el = lane & 31;
  const int hl = (H == 2) ? (lane >> 5) : 0;

  const int base = rp[n];
  const int deg = rp[n + 1] - base;
  const float siv = si_g[(size_t)n * H + hl];

  const int soff = (H == 1) ? (lane >> 5) : 0;
  const int qoff = (H == 1) ? (lane >> 5) : (lane & 32);
  constexpr int STEP = (H == 2) ? 1 : 2;
  const unsigned int loff = (H == 2) ? (unsigned)lane * 2 : (unsigned)el * 2;

  float m = 0.f, den = 0.f, acc0 = 0.f, acc1 = 0.f;

  for (int start = 0; start < deg; start += 32) {
    const int k = start + el;
    const bool vld = k < deg;
    const int s = vld ? col[base + k] : 0;
    float al = -INFINITY;
    if (vld) {
      const float t = siv + sj_g[(size_t)s * H + hl];
      al = (t > 0.f) ? t : 0.2f * t;
    }
    float cm = al;
#pragma unroll
    for (int o = 16; o; o >>= 1) cm = fmaxf(cm, __shfl_xor(cm, o, 64));
    if (start == 0) {
      m = cm;                      // first chunk: no rescale needed
    } else {
      const float nm = fmaxf(m, cm);
      const float r = __expf(m - nm);
      den *= r; acc0 *= r; acc1 *= r; m = nm;
    }
    const float p = vld ? __expf(al - m) : 0.f;
    float ps = p;
#pragma unroll
    for (int o = 16; o; o >>= 1) ps += __shfl_xor(ps, o, 64);
    den += ps;

    const int cc = min(32, deg - start);
    int kk = 0;
    for (; kk + 8 * STEP <= cc; kk += 8 * STEP) {
      int sb[8]; float qb[8]; unsigned int uv[8];
#pragma unroll
      for (int u = 0; u < 8; ++u) {
        const int e = kk + u * STEP;
        sb[u] = __shfl(s, e + soff, 64);
        qb[u] = __shfl(p, e + qoff, 64);
      }
#pragma unroll
      for (int u = 0; u < 8; ++u)
        uv[u] = *reinterpret_cast<const unsigned int*>(xh + (size_t)sb[u] * HC + loff);
#pragma unroll
      for (int u = 0; u < 8; ++u) {
        uf32 lo, hi;
        lo.u = uv[u] << 16;
        hi.u = uv[u] & 0xffff0000u;
        acc0 = fmaf(qb[u], lo.f, acc0);
        acc1 = fmaf(qb[u], hi.f, acc1);
      }
    }
    for (; kk + 4 * STEP <= cc; kk += 4 * STEP) {
      int sb[4]; float qb[4]; unsigned int uv[4];
#pragma unroll
      for (int u = 0; u < 4; ++u) {
        const int e = kk + u * STEP;
        sb[u] = __shfl(s, e + soff, 64);
        qb[u] = __shfl(p, e + qoff, 64);
      }
#pragma unroll
      for (int u = 0; u < 4; ++u)
        uv[u] = *reinterpret_cast<const unsigned int*>(xh + (size_t)sb[u] * HC + loff);
#pragma unroll
      for (int u = 0; u < 4; ++u) {
        uf32 lo, hi;
        lo.u = uv[u] << 16;
        hi.u = uv[u] & 0xffff0000u;
        acc0 = fmaf(qb[u], lo.f, acc0);
        acc1 = fmaf(qb[u], hi.f, acc1);
      }
    }
    for (; kk < cc; kk += STEP) {
      const int sb = __shfl(s, kk + soff, 64);
      const float qb = __shfl(p, kk + qoff, 64);
      const unsigned int uv = *reinterpret_cast<const unsigned int*>(xh + (size_t)sb * HC + loff);
      uf32 lo, hi;
      lo.u = uv << 16;
      hi.u = uv & 0xffff0000u;
      acc0 = fmaf(qb, lo.f, acc0);
      acc1 = fmaf(qb, hi.f, acc1);
    }
  }

  if (H == 2) {
    const float invd = 1.f / (den + 1e-16f);
    float v0 = acc0 * invd, v1 = acc1 * invd;
    v0 = (v0 > 0.f) ? v0 : expm1f(v0);
    v1 = (v1 > 0.f) ? v1 : expm1f(v1);
    if (OBF) {
      unsigned int pk = ((unsigned int)f2b(v1) << 16) | (unsigned int)f2b(v0);
      *reinterpret_cast<unsigned int*>((unsigned short*)out + (size_t)n * 128 + lane * 2) = pk;
    } else {
      float2 o; o.x = v0; o.y = v1;
      *reinterpret_cast<float2*>((float*)out + (size_t)n * 128 + lane * 2) = o;
    }
  } else {
    acc0 += __shfl_xor(acc0, 32, 64);
    acc1 += __shfl_xor(acc1, 32, 64);
    if (lane < 32) {
      const float invd = 1.f / (den + 1e-16f);
      float v0 = acc0 * invd, v1 = acc1 * invd;
      v0 = (v0 > 0.f) ? v0 : expm1f(v0);
      v1 = (v1 > 0.f) ? v1 : expm1f(v1);
      if (OBF) {
        unsigned int pk = ((unsigned int)f2b(v1) << 16) | (unsigned int)f2b(v0);
        *reinterpret_cast<unsigned int*>((unsigned short*)out + (size_t)n * 64 + el * 2) = pk;
      } else {
        float2 o; o.x = v0; o.y = v1;
        *reinterpret_cast<float2*>((float*)out + (size_t)n * 64 + el * 2) = o;
      }
    }
  }
}

// ---------------- launch ----------------
extern "C" void kernel_launch(void* const* d_in, const int* in_sizes, int n_in,
                              void* d_out, int out_size, void* d_ws, size_t ws_size,
                              hipStream_t stream) {
  const float* x     = (const float*)d_in[0];
  const int*   ei    = (const int*)d_in[1];
  const float* emb_w = (const float*)d_in[2];
  const float* emb_b = (const float*)d_in[3];
  const float* w0    = (const float*)d_in[4];
  const float* a0    = (const float*)d_in[5];
  const float* w1    = (const float*)d_in[6];
  const float* a1    = (const float*)d_in[7];
  const float* w2    = (const float*)d_in[8];
  const float* a2    = (const float*)d_in[9];

  const int IN_CH = 128;
  int N  = in_sizes[0] / IN_CH;   // 50000
  int E0 = in_sizes[1] / 2;       // 800000
  int E  = E0 + N;                // with self-loops

  // workspace carve (256B aligned)
  char* p = (char*)d_ws;
  auto alloc = [&](size_t bytes) -> char* {
    char* r = p;
    p += (bytes + 255) & ~(size_t)255;
    return r;
  };
  unsigned short* hA  = (unsigned short*)alloc((size_t)N * 128 * 2);
  unsigned short* hB  = (unsigned short*)alloc((size_t)N * 128 * 2);
  unsigned short* xhb = (unsigned short*)alloc((size_t)N * 128 * 2);
  float* si   = (float*)alloc((size_t)N * 2 * 4);
  float* sj   = (float*)alloc((size_t)N * 2 * 4);
  unsigned short* packE = (unsigned short*)alloc(128 * 64 * 2);
  unsigned short* pack0 = (unsigned short*)alloc(2 * 64 * 64 * 2);
  unsigned short* pack1 = (unsigned short*)alloc(2 * 128 * 64 * 2);
  unsigned short* pack2 = (unsigned short*)alloc(128 * 64 * 2);
  int* rp    = (int*)alloc((size_t)(N + 1) * 4);
  int* cnt   = (int*)alloc((size_t)N * 4);
  int* cnt8  = (int*)alloc((size_t)8 * N * 4);
  int* base8 = (int*)alloc((size_t)8 * N * 4);
  int* rb8   = (int*)alloc((size_t)8 * N * 4);
  unsigned short* lpos = (unsigned short*)alloc((size_t)E * 2);
  int* col   = (int*)alloc((size_t)E * 4);
  int* part  = (int*)alloc(1024);

  dim3 blk(256);
  int gN = (N + 255) / 256;     // 196
  int gE = (E + 255) / 256;
  int gZ = (8 * N + 255) / 256; // 1563

  // setup: zero cnt8 + all weight packs (one launch)
  setup_kernel<<<gZ + 160, blk, 0, stream>>>(cnt8, 8 * N, gZ,
                                             emb_w, w0, w1, w2,
                                             packE, pack0, pack1, pack2);
  // CSR build (atomic-light)
  hist8<<<gE, blk, 0, stream>>>(ei, cnt8, lpos, E0, N);
  fold8<<<gN, blk, 0, stream>>>(cnt8, base8, cnt, part, N);
  scan_carry<<<1, blk, 0, stream>>>(part, gN);
  scan3<<<gN, blk, 0, stream>>>(cnt, part, base8, rp, rb8, N, E);
  fillx<<<gE, blk, 0, stream>>>(ei, rb8, lpos, col, E0, N);

  int gR = (N + 63) / 64;  // 782

  // fused embedding + layer 0 (both heads), bf16 out + scores
  gemm_emb_l0<<<gR, blk, 0, stream>>>(x, packE, emb_b, pack0, a0, xhb, si, sj, N);
  agg_kernel<2, true><<<(N + 3) / 4, blk, 0, stream>>>(xhb, si, sj, rp, col, hB, N);

  // layer 1: F=128, H=2
  gemm_mfma<128, 2, true, true><<<gR, blk, 0, stream>>>(hB, pack1, a1, xhb, si, sj, N);
  agg_kernel<2, true><<<(N + 3) / 4, blk, 0, stream>>>(xhb, si, sj, rp, col, hA, N);

  // layer 2: F=128, H=1 -> output fp32
  gemm_mfma<128, 1, true, true><<<gR, blk, 0, stream>>>(hA, pack2, a2, xhb, si, sj, N);
  agg_kernel<1, false><<<(N + 3) / 4, blk, 0, stream>>>(xhb, si, sj, rp, col, (float*)d_out, N);
}

// Round 15
// 193.387 us; speedup vs baseline: 1.0631x; 1.0351x over previous
//
#include <hip/hip_runtime.h>
#include <math.h>

typedef __attribute__((ext_vector_type(8))) short short8v;   // 8 bf16 (4 VGPR)
typedef __attribute__((ext_vector_type(4))) float float4v;   // MFMA C/D frag

union uf32 { unsigned int u; float f; };

__device__ __forceinline__ unsigned short f2b(float f) {  // fp32 -> bf16 RNE
  uf32 v; v.f = f;
  unsigned int u = v.u;
  return (unsigned short)((u + 0x7fffu + ((u >> 16) & 1u)) >> 16);
}

// ================= CSR build (XCD-local atomics, atomic-free scatter) =======

// Per-virtual-XCD histogram; records each edge's local position (removes the
// atomic from the fill pass). vx = blockIdx.x & 7 = (e>>8)&7 matches the
// default round-robin block->XCD mapping, so atomics on cnt8[vx] stay
// XCD-local.
__global__ void hist8(const int* __restrict__ ei, int* __restrict__ cnt8,
                      unsigned short* __restrict__ lpos, int E0, int N) {
  int e = blockIdx.x * 256 + threadIdx.x;
  if (e >= E0 + N) return;
  int vx = blockIdx.x & 7;
  int d = (e < E0) ? ei[E0 + e] : (e - E0);
  lpos[e] = (unsigned short)atomicAdd(&cnt8[vx * N + d], 1);
}

// Fold per-XCD counts -> total degree + per-XCD exclusive base; fused
// block-reduction of degrees into part[].
__global__ void fold8(const int* __restrict__ cnt8, int* __restrict__ base8,
                      int* __restrict__ cnt, int* __restrict__ part, int N) {
  __shared__ int lds[256];
  int d = blockIdx.x * 256 + threadIdx.x;
  int run = 0;
  if (d < N) {
#pragma unroll
    for (int x = 0; x < 8; ++x) {
      int t = cnt8[x * N + d];
      base8[x * N + d] = run;
      run += t;
    }
    cnt[d] = run;
  }
  lds[threadIdx.x] = (d < N) ? run : 0;
  __syncthreads();
  for (int o = 128; o; o >>= 1) {
    if (threadIdx.x < o) lds[threadIdx.x] += lds[threadIdx.x + o];
    __syncthreads();
  }
  if (threadIdx.x == 0) part[blockIdx.x] = lds[0];
}

// single-block exclusive scan with carry (handles any nb)
__global__ void scan_carry(int* __restrict__ part, int nb) {
  __shared__ int lds[256];
  __shared__ int carry;
  if (threadIdx.x == 0) carry = 0;
  __syncthreads();
  for (int t0 = 0; t0 < nb; t0 += 256) {
    int t = t0 + threadIdx.x;
    int v = (t < nb) ? part[t] : 0;
    lds[threadIdx.x] = v;
    __syncthreads();
    for (int o = 1; o < 256; o <<= 1) {
      int x = (threadIdx.x >= o) ? lds[threadIdx.x - o] : 0;
      __syncthreads();
      lds[threadIdx.x] += x;
      __syncthreads();
    }
    if (t < nb) part[t] = carry + lds[threadIdx.x] - v;  // exclusive
    __syncthreads();
    if (threadIdx.x == 255) carry += lds[255];
    __syncthreads();
  }
}

// rp[] scan + fused rb8[x][d] = rp[d] + base8[x][d]
__global__ void scan3(const int* __restrict__ cnt, const int* __restrict__ part,
                      const int* __restrict__ base8, int* __restrict__ rp,
                      int* __restrict__ rb8, int N, int E) {
  __shared__ int lds[256];
  int t = threadIdx.x;
  int idx = blockIdx.x * 256 + t;
  int v = (idx < N) ? cnt[idx] : 0;
  lds[t] = v;
  __syncthreads();
  for (int o = 1; o < 256; o <<= 1) {
    int x = (t >= o) ? lds[t - o] : 0;
    __syncthreads();
    lds[t] += x;
    __syncthreads();
  }
  if (idx < N) {
    const int rpv = part[blockIdx.x] + lds[t] - v;
    rp[idx] = rpv;
#pragma unroll
    for (int x = 0; x < 8; ++x) rb8[x * N + idx] = rpv + base8[x * N + idx];
  }
  if (blockIdx.x == 0 && t == 0) rp[N] = E;
}

// ---------------- setup: zero cnt8 + all weight packs in ONE launch ---------
// blocks [0, gZ): zero cnt8 (8*N ints). blocks [gZ, gZ+160): weight packs.
// Pack element order ((kk*4+ct)*4+g)*128 + col*8 + j with f=kk*32+g*8+j,
// c=ct*16+col; fp32 [h][f][c] (strided) -> bf16 MFMA B-frags.
__global__ void setup_kernel(int* __restrict__ cnt8, int nz, int gZ,
                             const float* __restrict__ emb_w, const float* __restrict__ w0,
                             const float* __restrict__ w1, const float* __restrict__ w2,
                             unsigned short* __restrict__ pE, unsigned short* __restrict__ p0,
                             unsigned short* __restrict__ p1, unsigned short* __restrict__ p2) {
  if ((int)blockIdx.x < gZ) {
    int i = blockIdx.x * 256 + threadIdx.x;
    if (i < nz) cnt8[i] = 0;
    return;
  }
  int b = blockIdx.x - gZ;
  const float* w; unsigned short* bp;
  int F, sf, sc, h;
  if (b < 32)       { w = emb_w; bp = pE; F = 128; sf = 1;  sc = 128; h = 0; }
  else if (b < 64)  { b -= 32;  w = w0; bp = p0; F = 64;  sf = 64; sc = 1; h = b / 16; b %= 16; }
  else if (b < 128) { b -= 64;  w = w1; bp = p1; F = 128; sf = 64; sc = 1; h = b / 32; b %= 32; }
  else              { b -= 128; w = w2; bp = p2; F = 128; sf = 64; sc = 1; h = 0; }
  int i = b * 256 + threadIdx.x;
  if (i >= F * 64) return;
  int j = i & 7, colc = (i >> 3) & 15, g = (i >> 7) & 3, ct = (i >> 9) & 3, kk = i >> 11;
  int f = kk * 32 + g * 8 + j;
  int c = ct * 16 + colc;
  float v = w[(size_t)h * F * 64 + (size_t)f * sf + (size_t)c * sc];
  bp[(size_t)h * F * 64 + i] = f2b(v);
}

// ---------------- fused CSR-scatter + embedding + layer-0 GEMM --------------
// The two tails of the DAG's independent branches in one launch:
//   blocks [0, gR):        fused embedding + layer-0 MFMA (needs only packs)
//   blocks [gR, gR+gF):    fillx scatter (needs rb8/lpos from scan3)
// fillx's per-edge vx is computed from e directly ((e>>8)&7) so it matches
// hist8's mapping regardless of block placement. MFMA blocks overlap the
// scatter's memory latency on the same CUs.
__global__ __launch_bounds__(256) void fill_emb_l0(
    // fillx half
    const int* __restrict__ ei, const int* __restrict__ rb8,
    const unsigned short* __restrict__ lpos, int* __restrict__ col,
    int E0, int N, int gR,
    // gemm half
    const float* __restrict__ x, const unsigned short* __restrict__ packE,
    const float* __restrict__ emb_b, const unsigned short* __restrict__ pack0,
    const float* __restrict__ a0, unsigned short* __restrict__ xhb,
    float* __restrict__ si, float* __restrict__ sj) {
  constexpr int SA = 136;  // ushort stride for 128-wide stage
  constexpr int SB = 72;   // ushort stride for 64-wide emb-out
  __shared__ __align__(16) unsigned short lds[64 * SA];

  if ((int)blockIdx.x >= gR) {
    // ---- fillx role: atomic-free scatter ----
    const int e = (blockIdx.x - gR) * 256 + threadIdx.x;
    if (e >= E0 + N) return;
    const int vx = (e >> 8) & 7;  // same per-edge vx as hist8
    int s, d;
    if (e < E0) { s = ei[e]; d = ei[E0 + e]; }
    else        { s = e - E0; d = s; }
    col[rb8[vx * N + d] + lpos[e]] = s;
    return;
  }

  // ---- gemm_emb_l0 role ----
  const int nrows = N;
  const int tid = threadIdx.x;
  const int lane = tid & 63;
  const int wv = tid >> 6;
  const int n0 = blockIdx.x * 64;

  // stage x: 64 rows x 128 fp32 -> bf16
#pragma unroll
  for (int i0 = 0; i0 < 64 * 32; i0 += 256) {
    const int i = i0 + tid;
    const int row = i >> 5, c4 = i & 31;
    int rg = n0 + row;
    if (rg >= nrows) rg = nrows - 1;
    const float4 v = *reinterpret_cast<const float4*>(x + (size_t)rg * 128 + c4 * 4);
    unsigned short* d = lds + row * SA + c4 * 4;
    d[0] = f2b(v.x); d[1] = f2b(v.y); d[2] = f2b(v.z); d[3] = f2b(v.w);
  }
  __syncthreads();

  const int g = lane >> 4;
  const int cl = lane & 15;

  short8v xf[4];
  {
    const unsigned short* ar = lds + (wv * 16 + cl) * SA + g * 8;
#pragma unroll
    for (int kk = 0; kk < 4; ++kk) xf[kk] = *reinterpret_cast<const short8v*>(ar + kk * 32);
  }

  float4v eacc[4];
#pragma unroll
  for (int ct = 0; ct < 4; ++ct) eacc[ct] = (float4v){0.f, 0.f, 0.f, 0.f};
#pragma unroll
  for (int kk = 0; kk < 4; ++kk) {
#pragma unroll
    for (int ct = 0; ct < 4; ++ct) {
      const short8v bf = *reinterpret_cast<const short8v*>(
          packE + ((size_t)((kk * 4 + ct) * 4 + g)) * 128 + cl * 8);
      eacc[ct] = __builtin_amdgcn_mfma_f32_16x16x32_bf16(xf[kk], bf, eacc[ct], 0, 0, 0);
    }
  }
  __syncthreads();  // all waves done reading staged x

  // emb result (+bias) -> LDS bf16 (the layer-0 A tile)
#pragma unroll
  for (int ct = 0; ct < 4; ++ct) {
    const float b = emb_b[ct * 16 + cl];
#pragma unroll
    for (int reg = 0; reg < 4; ++reg) {
      const int row = wv * 16 + g * 4 + reg;
      lds[row * SB + ct * 16 + cl] = f2b(eacc[ct][reg] + b);
    }
  }
  __syncthreads();

  short8v af[2];
  {
    const unsigned short* ar2 = lds + (wv * 16 + cl) * SB + g * 8;
#pragma unroll
    for (int kk = 0; kk < 2; ++kk) af[kk] = *reinterpret_cast<const short8v*>(ar2 + kk * 32);
  }

#pragma unroll
  for (int h = 0; h < 2; ++h) {
    const unsigned short* __restrict__ bph = pack0 + (size_t)h * (64 * 64);

    float4v acc[4];
#pragma unroll
    for (int ct = 0; ct < 4; ++ct) acc[ct] = (float4v){0.f, 0.f, 0.f, 0.f};
#pragma unroll
    for (int kk = 0; kk < 2; ++kk) {
#pragma unroll
      for (int ct = 0; ct < 4; ++ct) {
        const short8v bf = *reinterpret_cast<const short8v*>(
            bph + ((size_t)((kk * 4 + ct) * 4 + g)) * 128 + cl * 8);
        acc[ct] = __builtin_amdgcn_mfma_f32_16x16x32_bf16(af[kk], bf, acc[ct], 0, 0, 0);
      }
    }

    // store bf16 xh
#pragma unroll
    for (int ct = 0; ct < 4; ++ct) {
      const int c = ct * 16 + cl;
#pragma unroll
      for (int reg = 0; reg < 4; ++reg) {
        const int n = n0 + wv * 16 + g * 4 + reg;
        if (n < nrows) xhb[(size_t)n * 128 + h * 64 + c] = f2b(acc[ct][reg]);
      }
    }

    // scores
    float pi[4] = {0.f, 0.f, 0.f, 0.f}, pj[4] = {0.f, 0.f, 0.f, 0.f};
#pragma unroll
    for (int ct = 0; ct < 4; ++ct) {
      const float av = a0[h * 128 + ct * 16 + cl];
      const float bv = a0[h * 128 + 64 + ct * 16 + cl];
#pragma unroll
      for (int reg = 0; reg < 4; ++reg) {
        pi[reg] = fmaf(acc[ct][reg], av, pi[reg]);
        pj[reg] = fmaf(acc[ct][reg], bv, pj[reg]);
      }
    }
#pragma unroll
    for (int reg = 0; reg < 4; ++reg) {
#pragma unroll
      for (int o = 8; o; o >>= 1) {
        pi[reg] += __shfl_xor(pi[reg], o, 64);
        pj[reg] += __shfl_xor(pj[reg], o, 64);
      }
    }
    if (cl == 0) {
#pragma unroll
      for (int reg = 0; reg < 4; ++reg) {
        const int n = n0 + wv * 16 + g * 4 + reg;
        if (n < nrows) {
          si[(size_t)n * 2 + h] = pi[reg];
          sj[(size_t)n * 2 + h] = pj[reg];
        }
      }
    }
  }
}

// ---------------- MFMA GEMM + attention scores (all heads per block) --------
// Block: 256 threads (4 waves), 64-row tile; loops h=0..H-1 with A-frags held
// in registers. B-frags from packed global (L2-hot). bf16 in, fp32 acc.
template <int F, int H, bool SCORES, bool OBF>
__global__ __launch_bounds__(256) void gemm_mfma(
    const unsigned short* __restrict__ in, const unsigned short* __restrict__ bp,
    const float* __restrict__ a, void* __restrict__ xh_out,
    float* __restrict__ si, float* __restrict__ sj, int nrows) {
  constexpr int SA = F + 8;
  constexpr int NK = F / 32;
  constexpr int HC = H * 64;
  __shared__ __align__(16) unsigned short A_lds[64 * SA];

  const int tid = threadIdx.x;
  const int lane = tid & 63;
  const int wv = tid >> 6;
  const int n0 = blockIdx.x * 64;

  {
    constexpr int NCH = 64 * F / 8;
#pragma unroll
    for (int i0 = 0; i0 < NCH; i0 += 256) {
      const int i = i0 + tid;
      const int row = i / (F / 8);
      const int c8 = i % (F / 8);
      int rg = n0 + row;
      if (rg >= nrows) rg = nrows - 1;
      const short8v v = *reinterpret_cast<const short8v*>(in + (size_t)rg * F + c8 * 8);
      *reinterpret_cast<short8v*>(A_lds + row * SA + c8 * 8) = v;
    }
  }
  __syncthreads();

  const int g = lane >> 4;
  const int cl = lane & 15;

  short8v af[NK];
  const unsigned short* ar = A_lds + (wv * 16 + cl) * SA + g * 8;
#pragma unroll
  for (int kk = 0; kk < NK; ++kk) af[kk] = *reinterpret_cast<const short8v*>(ar + kk * 32);

#pragma unroll
  for (int h = 0; h < H; ++h) {
    const unsigned short* __restrict__ bph = bp + (size_t)h * (F * 64);

    float4v acc[4];
#pragma unroll
    for (int ct = 0; ct < 4; ++ct) acc[ct] = (float4v){0.f, 0.f, 0.f, 0.f};

#pragma unroll
    for (int kk = 0; kk < NK; ++kk) {
#pragma unroll
      for (int ct = 0; ct < 4; ++ct) {
        const short8v bf = *reinterpret_cast<const short8v*>(
            bph + ((size_t)((kk * 4 + ct) * 4 + g)) * 128 + cl * 8);
        acc[ct] = __builtin_amdgcn_mfma_f32_16x16x32_bf16(af[kk], bf, acc[ct], 0, 0, 0);
      }
    }

#pragma unroll
    for (int ct = 0; ct < 4; ++ct) {
      const int c = ct * 16 + cl;
#pragma unroll
      for (int reg = 0; reg < 4; ++reg) {
        const int n = n0 + wv * 16 + g * 4 + reg;
        if (n < nrows) {
          const size_t idx = (size_t)n * HC + h * 64 + c;
          if (OBF) ((unsigned short*)xh_out)[idx] = f2b(acc[ct][reg]);
          else     ((float*)xh_out)[idx] = acc[ct][reg];
        }
      }
    }

    if (SCORES) {
      float pi[4] = {0.f, 0.f, 0.f, 0.f}, pj[4] = {0.f, 0.f, 0.f, 0.f};
#pragma unroll
      for (int ct = 0; ct < 4; ++ct) {
        const float av = a[h * 128 + ct * 16 + cl];
        const float bv = a[h * 128 + 64 + ct * 16 + cl];
#pragma unroll
        for (int reg = 0; reg < 4; ++reg) {
          pi[reg] = fmaf(acc[ct][reg], av, pi[reg]);
          pj[reg] = fmaf(acc[ct][reg], bv, pj[reg]);
        }
      }
#pragma unroll
      for (int reg = 0; reg < 4; ++reg) {
#pragma unroll
        for (int o = 8; o; o >>= 1) {
          pi[reg] += __shfl_xor(pi[reg], o, 64);
          pj[reg] += __shfl_xor(pj[reg], o, 64);
        }
      }
      if (cl == 0) {
#pragma unroll
        for (int reg = 0; reg < 4; ++reg) {
          const int n = n0 + wv * 16 + g * 4 + reg;
          if (n < nrows) {
            si[(size_t)n * H + h] = pi[reg];
            sj[(size_t)n * H + h] = pj[reg];
          }
        }
      }
    }
  }
}

// ---------------- per-node online-softmax aggregation (shfl broadcast) ------
// One wave per node, 32-edge chunks (round-12 verified best: pipelinable
// ds_bpermute broadcasts, uint gather, 8-deep unroll, first-chunk max skip).
// H==2: lane half = head; lane loads uint (2 bf16) -> one coalesced 256 B row
// per edge. H==1: halves process alternate edges; final shfl_xor(32) combine.
template <int H, bool OBF>
__global__ __launch_bounds__(256) void agg_kernel(
    const unsigned short* __restrict__ xh, const float* __restrict__ si_g,
    const float* __restrict__ sj_g, const int* __restrict__ rp,
    const int* __restrict__ col, void* __restrict__ out, int N) {
  constexpr int HC = H * 64;
  const int lane = threadIdx.x & 63;
  const int n = blockIdx.x * 4 + (threadIdx.x >> 6);
  if (n >= N) return;
  const int el = lane & 31;
  const int hl = (H == 2) ? (lane >> 5) : 0;

  const int base = rp[n];
  const int deg = rp[n + 1] - base;
  const float siv = si_g[(size_t)n * H + hl];

  const int soff = (H == 1) ? (lane >> 5) : 0;
  const int qoff = (H == 1) ? (lane >> 5) : (lane & 32);
  constexpr int STEP = (H == 2) ? 1 : 2;
  const unsigned int loff = (H == 2) ? (unsigned)lane * 2 : (unsigned)el * 2;

  float m = 0.f, den = 0.f, acc0 = 0.f, acc1 = 0.f;

  for (int start = 0; start < deg; start += 32) {
    const int k = start + el;
    const bool vld = k < deg;
    const int s = vld ? col[base + k] : 0;
    float al = -INFINITY;
    if (vld) {
      const float t = siv + sj_g[(size_t)s * H + hl];
      al = (t > 0.f) ? t : 0.2f * t;
    }
    float cm = al;
#pragma unroll
    for (int o = 16; o; o >>= 1) cm = fmaxf(cm, __shfl_xor(cm, o, 64));
    if (start == 0) {
      m = cm;                      // first chunk: no rescale needed
    } else {
      const float nm = fmaxf(m, cm);
      const float r = __expf(m - nm);
      den *= r; acc0 *= r; acc1 *= r; m = nm;
    }
    const float p = vld ? __expf(al - m) : 0.f;
    float ps = p;
#pragma unroll
    for (int o = 16; o; o >>= 1) ps += __shfl_xor(ps, o, 64);
    den += ps;

    const int cc = min(32, deg - start);
    int kk = 0;
    for (; kk + 8 * STEP <= cc; kk += 8 * STEP) {
      int sb[8]; float qb[8]; unsigned int uv[8];
#pragma unroll
      for (int u = 0; u < 8; ++u) {
        const int e = kk + u * STEP;
        sb[u] = __shfl(s, e + soff, 64);
        qb[u] = __shfl(p, e + qoff, 64);
      }
#pragma unroll
      for (int u = 0; u < 8; ++u)
        uv[u] = *reinterpret_cast<const unsigned int*>(xh + (size_t)sb[u] * HC + loff);
#pragma unroll
      for (int u = 0; u < 8; ++u) {
        uf32 lo, hi;
        lo.u = uv[u] << 16;
        hi.u = uv[u] & 0xffff0000u;
        acc0 = fmaf(qb[u], lo.f, acc0);
        acc1 = fmaf(qb[u], hi.f, acc1);
      }
    }
    for (; kk + 4 * STEP <= cc; kk += 4 * STEP) {
      int sb[4]; float qb[4]; unsigned int uv[4];
#pragma unroll
      for (int u = 0; u < 4; ++u) {
        const int e = kk + u * STEP;
        sb[u] = __shfl(s, e + soff, 64);
        qb[u] = __shfl(p, e + qoff, 64);
      }
#pragma unroll
      for (int u = 0; u < 4; ++u)
        uv[u] = *reinterpret_cast<const unsigned int*>(xh + (size_t)sb[u] * HC + loff);
#pragma unroll
      for (int u = 0; u < 4; ++u) {
        uf32 lo, hi;
        lo.u = uv[u] << 16;
        hi.u = uv[u] & 0xffff0000u;
        acc0 = fmaf(qb[u], lo.f, acc0);
        acc1 = fmaf(qb[u], hi.f, acc1);
      }
    }
    for (; kk < cc; kk += STEP) {
      const int sb = __shfl(s, kk + soff, 64);
      const float qb = __shfl(p, kk + qoff, 64);
      const unsigned int uv = *reinterpret_cast<const unsigned int*>(xh + (size_t)sb * HC + loff);
      uf32 lo, hi;
      lo.u = uv << 16;
      hi.u = uv & 0xffff0000u;
      acc0 = fmaf(qb, lo.f, acc0);
      acc1 = fmaf(qb, hi.f, acc1);
    }
  }

  if (H == 2) {
    const float invd = 1.f / (den + 1e-16f);
    float v0 = acc0 * invd, v1 = acc1 * invd;
    v0 = (v0 > 0.f) ? v0 : expm1f(v0);
    v1 = (v1 > 0.f) ? v1 : expm1f(v1);
    if (OBF) {
      unsigned int pk = ((unsigned int)f2b(v1) << 16) | (unsigned int)f2b(v0);
      *reinterpret_cast<unsigned int*>((unsigned short*)out + (size_t)n * 128 + lane * 2) = pk;
    } else {
      float2 o; o.x = v0; o.y = v1;
      *reinterpret_cast<float2*>((float*)out + (size_t)n * 128 + lane * 2) = o;
    }
  } else {
    acc0 += __shfl_xor(acc0, 32, 64);
    acc1 += __shfl_xor(acc1, 32, 64);
    if (lane < 32) {
      const float invd = 1.f / (den + 1e-16f);
      float v0 = acc0 * invd, v1 = acc1 * invd;
      v0 = (v0 > 0.f) ? v0 : expm1f(v0);
      v1 = (v1 > 0.f) ? v1 : expm1f(v1);
      if (OBF) {
        unsigned int pk = ((unsigned int)f2b(v1) << 16) | (unsigned int)f2b(v0);
        *reinterpret_cast<unsigned int*>((unsigned short*)out + (size_t)n * 64 + el * 2) = pk;
      } else {
        float2 o; o.x = v0; o.y = v1;
        *reinterpret_cast<float2*>((float*)out + (size_t)n * 64 + el * 2) = o;
      }
    }
  }
}

// ---------------- launch ----------------
extern "C" void kernel_launch(void* const* d_in, const int* in_sizes, int n_in,
                              void* d_out, int out_size, void* d_ws, size_t ws_size,
                              hipStream_t stream) {
  const float* x     = (const float*)d_in[0];
  const int*   ei    = (const int*)d_in[1];
  const float* emb_w = (const float*)d_in[2];
  const float* emb_b = (const float*)d_in[3];
  const float* w0    = (const float*)d_in[4];
  const float* a0    = (const float*)d_in[5];
  const float* w1    = (const float*)d_in[6];
  const float* a1    = (const float*)d_in[7];
  const float* w2    = (const float*)d_in[8];
  const float* a2    = (const float*)d_in[9];

  const int IN_CH = 128;
  int N  = in_sizes[0] / IN_CH;   // 50000
  int E0 = in_sizes[1] / 2;       // 800000
  int E  = E0 + N;                // with self-loops

  // workspace carve (256B aligned)
  char* p = (char*)d_ws;
  auto alloc = [&](size_t bytes) -> char* {
    char* r = p;
    p += (bytes + 255) & ~(size_t)255;
    return r;
  };
  unsigned short* hA  = (unsigned short*)alloc((size_t)N * 128 * 2);
  unsigned short* hB  = (unsigned short*)alloc((size_t)N * 128 * 2);
  unsigned short* xhb = (unsigned short*)alloc((size_t)N * 128 * 2);
  float* si   = (float*)alloc((size_t)N * 2 * 4);
  float* sj   = (float*)alloc((size_t)N * 2 * 4);
  unsigned short* packE = (unsigned short*)alloc(128 * 64 * 2);
  unsigned short* pack0 = (unsigned short*)alloc(2 * 64 * 64 * 2);
  unsigned short* pack1 = (unsigned short*)alloc(2 * 128 * 64 * 2);
  unsigned short* pack2 = (unsigned short*)alloc(128 * 64 * 2);
  int* rp    = (int*)alloc((size_t)(N + 1) * 4);
  int* cnt   = (int*)alloc((size_t)N * 4);
  int* cnt8  = (int*)alloc((size_t)8 * N * 4);
  int* base8 = (int*)alloc((size_t)8 * N * 4);
  int* rb8   = (int*)alloc((size_t)8 * N * 4);
  unsigned short* lpos = (unsigned short*)alloc((size_t)E * 2);
  int* col   = (int*)alloc((size_t)E * 4);
  int* part  = (int*)alloc(1024);

  dim3 blk(256);
  int gN = (N + 255) / 256;     // 196
  int gE = (E + 255) / 256;     // 3322
  int gZ = (8 * N + 255) / 256; // 1563
  int gR = (N + 63) / 64;       // 782

  // setup: zero cnt8 + all weight packs (one launch)
  setup_kernel<<<gZ + 160, blk, 0, stream>>>(cnt8, 8 * N, gZ,
                                             emb_w, w0, w1, w2,
                                             packE, pack0, pack1, pack2);
  // CSR build (atomic-light)
  hist8<<<gE, blk, 0, stream>>>(ei, cnt8, lpos, E0, N);
  fold8<<<gN, blk, 0, stream>>>(cnt8, base8, cnt, part, N);
  scan_carry<<<1, blk, 0, stream>>>(part, gN);
  scan3<<<gN, blk, 0, stream>>>(cnt, part, base8, rp, rb8, N, E);

  // fused: CSR scatter + embedding + layer-0 GEMM (independent DAG branches)
  fill_emb_l0<<<gR + gE, blk, 0, stream>>>(ei, rb8, lpos, col, E0, N, gR,
                                           x, packE, emb_b, pack0, a0, xhb, si, sj);
  agg_kernel<2, true><<<(N + 3) / 4, blk, 0, stream>>>(xhb, si, sj, rp, col, hB, N);

  // layer 1: F=128, H=2
  gemm_mfma<128, 2, true, true><<<gR, blk, 0, stream>>>(hB, pack1, a1, xhb, si, sj, N);
  agg_kernel<2, true><<<(N + 3) / 4, blk, 0, stream>>>(xhb, si, sj, rp, col, hA, N);

  // layer 2: F=128, H=1 -> output fp32
  gemm_mfma<128, 1, true, true><<<gR, blk, 0, stream>>>(hA, pack2, a2, xhb, si, sj, N);
  agg_kernel<1, false><<<(N + 3) / 4, blk, 0, stream>>>(xhb, si, sj, rp, col, (float*)d_out, N);
}

// Round 16
// 192.480 us; speedup vs baseline: 1.0681x; 1.0047x over previous
//
#include <hip/hip_runtime.h>
#include <math.h>

typedef __attribute__((ext_vector_type(8))) short short8v;   // 8 bf16 (4 VGPR)
typedef __attribute__((ext_vector_type(4))) float float4v;   // MFMA C/D frag

union uf32 { unsigned int u; float f; };

__device__ __forceinline__ unsigned short f2b(float f) {  // fp32 -> bf16 RNE
  uf32 v; v.f = f;
  unsigned int u = v.u;
  return (unsigned short)((u + 0x7fffu + ((u >> 16) & 1u)) >> 16);
}

// ================= CSR build (XCD-local atomics, atomic-free scatter) =======

// Per-virtual-XCD histogram; records each edge's local position (removes the
// atomic from the fill pass). vx = blockIdx.x & 7 = (e>>8)&7 matches the
// default round-robin block->XCD mapping, so atomics on cnt8[vx] stay
// XCD-local.
__global__ void hist8(const int* __restrict__ ei, int* __restrict__ cnt8,
                      unsigned short* __restrict__ lpos, int E0, int N) {
  int e = blockIdx.x * 256 + threadIdx.x;
  if (e >= E0 + N) return;
  int vx = blockIdx.x & 7;
  int d = (e < E0) ? ei[E0 + e] : (e - E0);
  lpos[e] = (unsigned short)atomicAdd(&cnt8[vx * N + d], 1);
}

// ---------------- single-pass CSR scan (decoupled lookback) -----------------
// Replaces fold8 + scan_carry + scan3. Block b handles d in [b*256,(b+1)*256).
// Per-thread: fold cnt8 -> degree run + per-XCD bases (registers only).
// Block aggregate posted as (1<<24)|agg in flags[b]; wave-parallel lookback
// (64 flags per probe) resolves exclusive prefix; final flag (2<<24)|prefix.
// Scan values ride inside the flag word (max E=850001 < 2^24) -> relaxed
// atomics are sufficient; output is deterministic for any dispatch order.
// All 196 blocks co-resident (<< capacity) -> spin is deadlock-free.
__global__ __launch_bounds__(256) void scan_fused(
    const int* __restrict__ cnt8, int* __restrict__ rp, int* __restrict__ rb8,
    unsigned int* __restrict__ flags, int N, int E) {
  __shared__ int lds[256];
  __shared__ int s_excl;
  const int b = blockIdx.x;
  const int t = threadIdx.x;
  const int d = b * 256 + t;

  int run = 0;
  int b8[8];
  if (d < N) {
#pragma unroll
    for (int x = 0; x < 8; ++x) {
      b8[x] = run;
      run += cnt8[x * N + d];
    }
  }

  // block aggregate
  lds[t] = (d < N) ? run : 0;
  __syncthreads();
  for (int o = 128; o; o >>= 1) {
    if (t < o) lds[t] += lds[t + o];
    __syncthreads();
  }
  const int aggregate = lds[0];
  if (t == 0)
    __hip_atomic_store(&flags[b], (1u << 24) | (unsigned)aggregate,
                       __ATOMIC_RELAXED, __HIP_MEMORY_SCOPE_AGENT);
  __syncthreads();

  // wave-parallel lookback (first wave only)
  if (t < 64) {
    int excl = 0;
    int wstart = b - 1;
    while (wstart >= 0) {
      const int myb = wstart - t;
      unsigned v = 0;
      if (myb >= 0) {
        do {
          v = __hip_atomic_load(&flags[myb], __ATOMIC_RELAXED, __HIP_MEMORY_SCOPE_AGENT);
        } while ((v >> 24) == 0u);
      }
      const unsigned long long pm = __ballot(myb >= 0 && (v >> 24) == 2u);
      const int firstP = pm ? (__ffsll((long long)pm) - 1) : 64;
      int c = (myb >= 0 && t <= firstP) ? (int)(v & 0xFFFFFFu) : 0;
#pragma unroll
      for (int o = 32; o; o >>= 1) c += __shfl_xor(c, o, 64);
      excl += c;
      if (firstP < 64) break;
      wstart -= 64;
    }
    if (t == 0) {
      s_excl = excl;
      __hip_atomic_store(&flags[b], (2u << 24) | (unsigned)(excl + aggregate),
                         __ATOMIC_RELAXED, __HIP_MEMORY_SCOPE_AGENT);
    }
  }
  __syncthreads();
  const int excl = s_excl;

  // block-local exclusive scan of degrees + outputs
  lds[t] = (d < N) ? run : 0;
  __syncthreads();
  for (int o = 1; o < 256; o <<= 1) {
    int x = (t >= o) ? lds[t - o] : 0;
    __syncthreads();
    lds[t] += x;
    __syncthreads();
  }
  if (d < N) {
    const int rpv = excl + lds[t] - run;
    rp[d] = rpv;
#pragma unroll
    for (int x = 0; x < 8; ++x) rb8[x * N + d] = rpv + b8[x];
  }
  if (b == 0 && t == 0) rp[N] = E;
}

// ---------------- setup: zero cnt8+flags + all weight packs in ONE launch ---
// blocks [0, gZ): zero cnt8 (8*N ints) + scan flags (256 ints, contiguous).
// blocks [gZ, gZ+160): weight packs. Pack element order
// ((kk*4+ct)*4+g)*128 + col*8 + j with f=kk*32+g*8+j, c=ct*16+col;
// fp32 [h][f][c] (strided) -> bf16 MFMA B-frags.
__global__ void setup_kernel(int* __restrict__ cnt8, int nz, int gZ,
                             const float* __restrict__ emb_w, const float* __restrict__ w0,
                             const float* __restrict__ w1, const float* __restrict__ w2,
                             unsigned short* __restrict__ pE, unsigned short* __restrict__ p0,
                             unsigned short* __restrict__ p1, unsigned short* __restrict__ p2) {
  if ((int)blockIdx.x < gZ) {
    int i = blockIdx.x * 256 + threadIdx.x;
    if (i < nz) cnt8[i] = 0;
    return;
  }
  int b = blockIdx.x - gZ;
  const float* w; unsigned short* bp;
  int F, sf, sc, h;
  if (b < 32)       { w = emb_w; bp = pE; F = 128; sf = 1;  sc = 128; h = 0; }
  else if (b < 64)  { b -= 32;  w = w0; bp = p0; F = 64;  sf = 64; sc = 1; h = b / 16; b %= 16; }
  else if (b < 128) { b -= 64;  w = w1; bp = p1; F = 128; sf = 64; sc = 1; h = b / 32; b %= 32; }
  else              { b -= 128; w = w2; bp = p2; F = 128; sf = 64; sc = 1; h = 0; }
  int i = b * 256 + threadIdx.x;
  if (i >= F * 64) return;
  int j = i & 7, colc = (i >> 3) & 15, g = (i >> 7) & 3, ct = (i >> 9) & 3, kk = i >> 11;
  int f = kk * 32 + g * 8 + j;
  int c = ct * 16 + colc;
  float v = w[(size_t)h * F * 64 + (size_t)f * sf + (size_t)c * sc];
  bp[(size_t)h * F * 64 + i] = f2b(v);
}

// ---------------- fused CSR-scatter + embedding + layer-0 GEMM --------------
// blocks [0, gR): fused embedding + layer-0 MFMA (needs only packs).
// blocks [gR, gR+gE): fillx scatter (needs rb8/lpos). fillx's per-edge vx is
// computed from e directly ((e>>8)&7) so it matches hist8's mapping.
__global__ __launch_bounds__(256) void fill_emb_l0(
    // fillx half
    const int* __restrict__ ei, const int* __restrict__ rb8,
    const unsigned short* __restrict__ lpos, int* __restrict__ col,
    int E0, int N, int gR,
    // gemm half
    const float* __restrict__ x, const unsigned short* __restrict__ packE,
    const float* __restrict__ emb_b, const unsigned short* __restrict__ pack0,
    const float* __restrict__ a0, unsigned short* __restrict__ xhb,
    float* __restrict__ si, float* __restrict__ sj) {
  constexpr int SA = 136;  // ushort stride for 128-wide stage
  constexpr int SB = 72;   // ushort stride for 64-wide emb-out
  __shared__ __align__(16) unsigned short lds[64 * SA];

  if ((int)blockIdx.x >= gR) {
    // ---- fillx role: atomic-free scatter ----
    const int e = (blockIdx.x - gR) * 256 + threadIdx.x;
    if (e >= E0 + N) return;
    const int vx = (e >> 8) & 7;  // same per-edge vx as hist8
    int s, d;
    if (e < E0) { s = ei[e]; d = ei[E0 + e]; }
    else        { s = e - E0; d = s; }
    col[rb8[vx * N + d] + lpos[e]] = s;
    return;
  }

  // ---- gemm_emb_l0 role ----
  const int nrows = N;
  const int tid = threadIdx.x;
  const int lane = tid & 63;
  const int wv = tid >> 6;
  const int n0 = blockIdx.x * 64;

  // stage x: 64 rows x 128 fp32 -> bf16
#pragma unroll
  for (int i0 = 0; i0 < 64 * 32; i0 += 256) {
    const int i = i0 + tid;
    const int row = i >> 5, c4 = i & 31;
    int rg = n0 + row;
    if (rg >= nrows) rg = nrows - 1;
    const float4 v = *reinterpret_cast<const float4*>(x + (size_t)rg * 128 + c4 * 4);
    unsigned short* d = lds + row * SA + c4 * 4;
    d[0] = f2b(v.x); d[1] = f2b(v.y); d[2] = f2b(v.z); d[3] = f2b(v.w);
  }
  __syncthreads();

  const int g = lane >> 4;
  const int cl = lane & 15;

  short8v xf[4];
  {
    const unsigned short* ar = lds + (wv * 16 + cl) * SA + g * 8;
#pragma unroll
    for (int kk = 0; kk < 4; ++kk) xf[kk] = *reinterpret_cast<const short8v*>(ar + kk * 32);
  }

  float4v eacc[4];
#pragma unroll
  for (int ct = 0; ct < 4; ++ct) eacc[ct] = (float4v){0.f, 0.f, 0.f, 0.f};
#pragma unroll
  for (int kk = 0; kk < 4; ++kk) {
#pragma unroll
    for (int ct = 0; ct < 4; ++ct) {
      const short8v bf = *reinterpret_cast<const short8v*>(
          packE + ((size_t)((kk * 4 + ct) * 4 + g)) * 128 + cl * 8);
      eacc[ct] = __builtin_amdgcn_mfma_f32_16x16x32_bf16(xf[kk], bf, eacc[ct], 0, 0, 0);
    }
  }
  __syncthreads();  // all waves done reading staged x

  // emb result (+bias) -> LDS bf16 (the layer-0 A tile)
#pragma unroll
  for (int ct = 0; ct < 4; ++ct) {
    const float b = emb_b[ct * 16 + cl];
#pragma unroll
    for (int reg = 0; reg < 4; ++reg) {
      const int row = wv * 16 + g * 4 + reg;
      lds[row * SB + ct * 16 + cl] = f2b(eacc[ct][reg] + b);
    }
  }
  __syncthreads();

  short8v af[2];
  {
    const unsigned short* ar2 = lds + (wv * 16 + cl) * SB + g * 8;
#pragma unroll
    for (int kk = 0; kk < 2; ++kk) af[kk] = *reinterpret_cast<const short8v*>(ar2 + kk * 32);
  }

#pragma unroll
  for (int h = 0; h < 2; ++h) {
    const unsigned short* __restrict__ bph = pack0 + (size_t)h * (64 * 64);

    float4v acc[4];
#pragma unroll
    for (int ct = 0; ct < 4; ++ct) acc[ct] = (float4v){0.f, 0.f, 0.f, 0.f};
#pragma unroll
    for (int kk = 0; kk < 2; ++kk) {
#pragma unroll
      for (int ct = 0; ct < 4; ++ct) {
        const short8v bf = *reinterpret_cast<const short8v*>(
            bph + ((size_t)((kk * 4 + ct) * 4 + g)) * 128 + cl * 8);
        acc[ct] = __builtin_amdgcn_mfma_f32_16x16x32_bf16(af[kk], bf, acc[ct], 0, 0, 0);
      }
    }

    // store bf16 xh
#pragma unroll
    for (int ct = 0; ct < 4; ++ct) {
      const int c = ct * 16 + cl;
#pragma unroll
      for (int reg = 0; reg < 4; ++reg) {
        const int n = n0 + wv * 16 + g * 4 + reg;
        if (n < nrows) xhb[(size_t)n * 128 + h * 64 + c] = f2b(acc[ct][reg]);
      }
    }

    // scores
    float pi[4] = {0.f, 0.f, 0.f, 0.f}, pj[4] = {0.f, 0.f, 0.f, 0.f};
#pragma unroll
    for (int ct = 0; ct < 4; ++ct) {
      const float av = a0[h * 128 + ct * 16 + cl];
      const float bv = a0[h * 128 + 64 + ct * 16 + cl];
#pragma unroll
      for (int reg = 0; reg < 4; ++reg) {
        pi[reg] = fmaf(acc[ct][reg], av, pi[reg]);
        pj[reg] = fmaf(acc[ct][reg], bv, pj[reg]);
      }
    }
#pragma unroll
    for (int reg = 0; reg < 4; ++reg) {
#pragma unroll
      for (int o = 8; o; o >>= 1) {
        pi[reg] += __shfl_xor(pi[reg], o, 64);
        pj[reg] += __shfl_xor(pj[reg], o, 64);
      }
    }
    if (cl == 0) {
#pragma unroll
      for (int reg = 0; reg < 4; ++reg) {
        const int n = n0 + wv * 16 + g * 4 + reg;
        if (n < nrows) {
          si[(size_t)n * 2 + h] = pi[reg];
          sj[(size_t)n * 2 + h] = pj[reg];
        }
      }
    }
  }
}

// ---------------- MFMA GEMM + attention scores (all heads per block) --------
// Block: 256 threads (4 waves), 64-row tile; loops h=0..H-1 with A-frags held
// in registers. B-frags from packed global (L2-hot). bf16 in, fp32 acc.
template <int F, int H, bool SCORES, bool OBF>
__global__ __launch_bounds__(256) void gemm_mfma(
    const unsigned short* __restrict__ in, const unsigned short* __restrict__ bp,
    const float* __restrict__ a, void* __restrict__ xh_out,
    float* __restrict__ si, float* __restrict__ sj, int nrows) {
  constexpr int SA = F + 8;
  constexpr int NK = F / 32;
  constexpr int HC = H * 64;
  __shared__ __align__(16) unsigned short A_lds[64 * SA];

  const int tid = threadIdx.x;
  const int lane = tid & 63;
  const int wv = tid >> 6;
  const int n0 = blockIdx.x * 64;

  {
    constexpr int NCH = 64 * F / 8;
#pragma unroll
    for (int i0 = 0; i0 < NCH; i0 += 256) {
      const int i = i0 + tid;
      const int row = i / (F / 8);
      const int c8 = i % (F / 8);
      int rg = n0 + row;
      if (rg >= nrows) rg = nrows - 1;
      const short8v v = *reinterpret_cast<const short8v*>(in + (size_t)rg * F + c8 * 8);
      *reinterpret_cast<short8v*>(A_lds + row * SA + c8 * 8) = v;
    }
  }
  __syncthreads();

  const int g = lane >> 4;
  const int cl = lane & 15;

  short8v af[NK];
  const unsigned short* ar = A_lds + (wv * 16 + cl) * SA + g * 8;
#pragma unroll
  for (int kk = 0; kk < NK; ++kk) af[kk] = *reinterpret_cast<const short8v*>(ar + kk * 32);

#pragma unroll
  for (int h = 0; h < H; ++h) {
    const unsigned short* __restrict__ bph = bp + (size_t)h * (F * 64);

    float4v acc[4];
#pragma unroll
    for (int ct = 0; ct < 4; ++ct) acc[ct] = (float4v){0.f, 0.f, 0.f, 0.f};

#pragma unroll
    for (int kk = 0; kk < NK; ++kk) {
#pragma unroll
      for (int ct = 0; ct < 4; ++ct) {
        const short8v bf = *reinterpret_cast<const short8v*>(
            bph + ((size_t)((kk * 4 + ct) * 4 + g)) * 128 + cl * 8);
        acc[ct] = __builtin_amdgcn_mfma_f32_16x16x32_bf16(af[kk], bf, acc[ct], 0, 0, 0);
      }
    }

#pragma unroll
    for (int ct = 0; ct < 4; ++ct) {
      const int c = ct * 16 + cl;
#pragma unroll
      for (int reg = 0; reg < 4; ++reg) {
        const int n = n0 + wv * 16 + g * 4 + reg;
        if (n < nrows) {
          const size_t idx = (size_t)n * HC + h * 64 + c;
          if (OBF) ((unsigned short*)xh_out)[idx] = f2b(acc[ct][reg]);
          else     ((float*)xh_out)[idx] = acc[ct][reg];
        }
      }
    }

    if (SCORES) {
      float pi[4] = {0.f, 0.f, 0.f, 0.f}, pj[4] = {0.f, 0.f, 0.f, 0.f};
#pragma unroll
      for (int ct = 0; ct < 4; ++ct) {
        const float av = a[h * 128 + ct * 16 + cl];
        const float bv = a[h * 128 + 64 + ct * 16 + cl];
#pragma unroll
        for (int reg = 0; reg < 4; ++reg) {
          pi[reg] = fmaf(acc[ct][reg], av, pi[reg]);
          pj[reg] = fmaf(acc[ct][reg], bv, pj[reg]);
        }
      }
#pragma unroll
      for (int reg = 0; reg < 4; ++reg) {
#pragma unroll
        for (int o = 8; o; o >>= 1) {
          pi[reg] += __shfl_xor(pi[reg], o, 64);
          pj[reg] += __shfl_xor(pj[reg], o, 64);
        }
      }
      if (cl == 0) {
#pragma unroll
        for (int reg = 0; reg < 4; ++reg) {
          const int n = n0 + wv * 16 + g * 4 + reg;
          if (n < nrows) {
            si[(size_t)n * H + h] = pi[reg];
            sj[(size_t)n * H + h] = pj[reg];
          }
        }
      }
    }
  }
}

// ---------------- per-node online-softmax aggregation (shfl broadcast) ------
// One wave per node, 32-edge chunks (round-12 verified best: pipelinable
// ds_bpermute broadcasts, uint gather, 8-deep unroll, first-chunk max skip).
// H==2: lane half = head; lane loads uint (2 bf16) -> one coalesced 256 B row
// per edge. H==1: halves process alternate edges; final shfl_xor(32) combine.
template <int H, bool OBF>
__global__ __launch_bounds__(256) void agg_kernel(
    const unsigned short* __restrict__ xh, const float* __restrict__ si_g,
    const float* __restrict__ sj_g, const int* __restrict__ rp,
    const int* __restrict__ col, void* __restrict__ out, int N) {
  constexpr int HC = H * 64;
  const int lane = threadIdx.x & 63;
  const int n = blockIdx.x * 4 + (threadIdx.x >> 6);
  if (n >= N) return;
  const int el = lane & 31;
  const int hl = (H == 2) ? (lane >> 5) : 0;

  const int base = rp[n];
  const int deg = rp[n + 1] - base;
  const float siv = si_g[(size_t)n * H + hl];

  const int soff = (H == 1) ? (lane >> 5) : 0;
  const int qoff = (H == 1) ? (lane >> 5) : (lane & 32);
  constexpr int STEP = (H == 2) ? 1 : 2;
  const unsigned int loff = (H == 2) ? (unsigned)lane * 2 : (unsigned)el * 2;

  float m = 0.f, den = 0.f, acc0 = 0.f, acc1 = 0.f;

  for (int start = 0; start < deg; start += 32) {
    const int k = start + el;
    const bool vld = k < deg;
    const int s = vld ? col[base + k] : 0;
    float al = -INFINITY;
    if (vld) {
      const float t = siv + sj_g[(size_t)s * H + hl];
      al = (t > 0.f) ? t : 0.2f * t;
    }
    float cm = al;
#pragma unroll
    for (int o = 16; o; o >>= 1) cm = fmaxf(cm, __shfl_xor(cm, o, 64));
    if (start == 0) {
      m = cm;                      // first chunk: no rescale needed
    } else {
      const float nm = fmaxf(m, cm);
      const float r = __expf(m - nm);
      den *= r; acc0 *= r; acc1 *= r; m = nm;
    }
    const float p = vld ? __expf(al - m) : 0.f;
    float ps = p;
#pragma unroll
    for (int o = 16; o; o >>= 1) ps += __shfl_xor(ps, o, 64);
    den += ps;

    const int cc = min(32, deg - start);
    int kk = 0;
    for (; kk + 8 * STEP <= cc; kk += 8 * STEP) {
      int sb[8]; float qb[8]; unsigned int uv[8];
#pragma unroll
      for (int u = 0; u < 8; ++u) {
        const int e = kk + u * STEP;
        sb[u] = __shfl(s, e + soff, 64);
        qb[u] = __shfl(p, e + qoff, 64);
      }
#pragma unroll
      for (int u = 0; u < 8; ++u)
        uv[u] = *reinterpret_cast<const unsigned int*>(xh + (size_t)sb[u] * HC + loff);
#pragma unroll
      for (int u = 0; u < 8; ++u) {
        uf32 lo, hi;
        lo.u = uv[u] << 16;
        hi.u = uv[u] & 0xffff0000u;
        acc0 = fmaf(qb[u], lo.f, acc0);
        acc1 = fmaf(qb[u], hi.f, acc1);
      }
    }
    for (; kk + 4 * STEP <= cc; kk += 4 * STEP) {
      int sb[4]; float qb[4]; unsigned int uv[4];
#pragma unroll
      for (int u = 0; u < 4; ++u) {
        const int e = kk + u * STEP;
        sb[u] = __shfl(s, e + soff, 64);
        qb[u] = __shfl(p, e + qoff, 64);
      }
#pragma unroll
      for (int u = 0; u < 4; ++u)
        uv[u] = *reinterpret_cast<const unsigned int*>(xh + (size_t)sb[u] * HC + loff);
#pragma unroll
      for (int u = 0; u < 4; ++u) {
        uf32 lo, hi;
        lo.u = uv[u] << 16;
        hi.u = uv[u] & 0xffff0000u;
        acc0 = fmaf(qb[u], lo.f, acc0);
        acc1 = fmaf(qb[u], hi.f, acc1);
      }
    }
    for (; kk < cc; kk += STEP) {
      const int sb = __shfl(s, kk + soff, 64);
      const float qb = __shfl(p, kk + qoff, 64);
      const unsigned int uv = *reinterpret_cast<const unsigned int*>(xh + (size_t)sb * HC + loff);
      uf32 lo, hi;
      lo.u = uv << 16;
      hi.u = uv & 0xffff0000u;
      acc0 = fmaf(qb, lo.f, acc0);
      acc1 = fmaf(qb, hi.f, acc1);
    }
  }

  if (H == 2) {
    const float invd = 1.f / (den + 1e-16f);
    float v0 = acc0 * invd, v1 = acc1 * invd;
    v0 = (v0 > 0.f) ? v0 : expm1f(v0);
    v1 = (v1 > 0.f) ? v1 : expm1f(v1);
    if (OBF) {
      unsigned int pk = ((unsigned int)f2b(v1) << 16) | (unsigned int)f2b(v0);
      *reinterpret_cast<unsigned int*>((unsigned short*)out + (size_t)n * 128 + lane * 2) = pk;
    } else {
      float2 o; o.x = v0; o.y = v1;
      *reinterpret_cast<float2*>((float*)out + (size_t)n * 128 + lane * 2) = o;
    }
  } else {
    acc0 += __shfl_xor(acc0, 32, 64);
    acc1 += __shfl_xor(acc1, 32, 64);
    if (lane < 32) {
      const float invd = 1.f / (den + 1e-16f);
      float v0 = acc0 * invd, v1 = acc1 * invd;
      v0 = (v0 > 0.f) ? v0 : expm1f(v0);
      v1 = (v1 > 0.f) ? v1 : expm1f(v1);
      if (OBF) {
        unsigned int pk = ((unsigned int)f2b(v1) << 16) | (unsigned int)f2b(v0);
        *reinterpret_cast<unsigned int*>((unsigned short*)out + (size_t)n * 64 + el * 2) = pk;
      } else {
        float2 o; o.x = v0; o.y = v1;
        *reinterpret_cast<float2*>((float*)out + (size_t)n * 64 + el * 2) = o;
      }
    }
  }
}

// ---------------- launch ----------------
extern "C" void kernel_launch(void* const* d_in, const int* in_sizes, int n_in,
                              void* d_out, int out_size, void* d_ws, size_t ws_size,
                              hipStream_t stream) {
  const float* x     = (const float*)d_in[0];
  const int*   ei    = (const int*)d_in[1];
  const float* emb_w = (const float*)d_in[2];
  const float* emb_b = (const float*)d_in[3];
  const float* w0    = (const float*)d_in[4];
  const float* a0    = (const float*)d_in[5];
  const float* w1    = (const float*)d_in[6];
  const float* a1    = (const float*)d_in[7];
  const float* w2    = (const float*)d_in[8];
  const float* a2    = (const float*)d_in[9];

  const int IN_CH = 128;
  int N  = in_sizes[0] / IN_CH;   // 50000
  int E0 = in_sizes[1] / 2;       // 800000
  int E  = E0 + N;                // with self-loops

  // workspace carve (256B aligned)
  char* p = (char*)d_ws;
  auto alloc = [&](size_t bytes) -> char* {
    char* r = p;
    p += (bytes + 255) & ~(size_t)255;
    return r;
  };
  unsigned short* hA  = (unsigned short*)alloc((size_t)N * 128 * 2);
  unsigned short* hB  = (unsigned short*)alloc((size_t)N * 128 * 2);
  unsigned short* xhb = (unsigned short*)alloc((size_t)N * 128 * 2);
  float* si   = (float*)alloc((size_t)N * 2 * 4);
  float* sj   = (float*)alloc((size_t)N * 2 * 4);
  unsigned short* packE = (unsigned short*)alloc(128 * 64 * 2);
  unsigned short* pack0 = (unsigned short*)alloc(2 * 64 * 64 * 2);
  unsigned short* pack1 = (unsigned short*)alloc(2 * 128 * 64 * 2);
  unsigned short* pack2 = (unsigned short*)alloc(128 * 64 * 2);
  int* rp    = (int*)alloc((size_t)(N + 1) * 4);
  int* cnt8  = (int*)alloc((size_t)(8 * N + 256) * 4);  // + scan flags
  unsigned int* flags = (unsigned int*)(cnt8 + 8 * N);
  int* rb8   = (int*)alloc((size_t)8 * N * 4);
  unsigned short* lpos = (unsigned short*)alloc((size_t)E * 2);
  int* col   = (int*)alloc((size_t)E * 4);

  dim3 blk(256);
  int gN = (N + 255) / 256;               // 196
  int gE = (E + 255) / 256;               // 3322
  int gZ = (8 * N + 256 + 255) / 256;     // zero cnt8 + flags
  int gR = (N + 63) / 64;                 // 782

  // setup: zero cnt8+flags + all weight packs (one launch)
  setup_kernel<<<gZ + 160, blk, 0, stream>>>(cnt8, 8 * N + 256, gZ,
                                             emb_w, w0, w1, w2,
                                             packE, pack0, pack1, pack2);
  // CSR build: histogram, then single-pass decoupled-lookback scan
  hist8<<<gE, blk, 0, stream>>>(ei, cnt8, lpos, E0, N);
  scan_fused<<<gN, blk, 0, stream>>>(cnt8, rp, rb8, flags, N, E);

  // fused: CSR scatter + embedding + layer-0 GEMM (independent DAG branches)
  fill_emb_l0<<<gR + gE, blk, 0, stream>>>(ei, rb8, lpos, col, E0, N, gR,
                                           x, packE, emb_b, pack0, a0, xhb, si, sj);
  agg_kernel<2, true><<<(N + 3) / 4, blk, 0, stream>>>(xhb, si, sj, rp, col, hB, N);

  // layer 1: F=128, H=2
  gemm_mfma<128, 2, true, true><<<gR, blk, 0, stream>>>(hB, pack1, a1, xhb, si, sj, N);
  agg_kernel<2, true><<<(N + 3) / 4, blk, 0, stream>>>(xhb, si, sj, rp, col, hA, N);

  // layer 2: F=128, H=1 -> output fp32
  gemm_mfma<128, 1, true, true><<<gR, blk, 0, stream>>>(hA, pack2, a2, xhb, si, sj, N);
  agg_kernel<1, false><<<(N + 3) / 4, blk, 0, stream>>>(xhb, si, sj, rp, col, (float*)d_out, N);
}